// Round 9
// baseline (547.187 us; speedup 1.0000x reference)
//
#include <hip/hip_runtime.h>
#include <hip/hip_bf16.h>
#include <math.h>

#define NS   4      // batch
#define CH   128    // channels
#define HW   96     // full-res H=W
#define GS   48     // half-res grid side
#define LL   2304   // GS*GS
#define CKN  2048   // CH*16 (4x4 taps)
#define SCALE 10.0f
#define EPSSUM 0.1152f  // 1152 * 1e-4
#define PCH2 32     // softmax p-chunk
#define NCH2 72     // 2304/32

// per-sample strides (elements)
#define S_IN  ((size_t)CH * HW * HW)   // b / f / out
#define S_MK  ((size_t)HW * HW)        // mask
#define S_BS  ((size_t)CH * LL)        // bs_c / fs_c
#define S_PM  ((size_t)NCH2 * LL)      // pmax / psum
#define S_BUF ((size_t)LL * LL)        // bufA / bufB (fp32)
#define S_W2  ((size_t)CKN * LL)       // W2T (bf16 elems)
#define S_AT  ((size_t)LL * LL)        // attnT (bf16 elems)

typedef __attribute__((ext_vector_type(8))) short short8;
typedef __attribute__((ext_vector_type(4))) float float4v;

#define GLDS16(gptr, lptr) \
    __builtin_amdgcn_global_load_lds((const __attribute__((address_space(1))) void*)(gptr), \
        (__attribute__((address_space(3))) void*)(lptr), 16, 0, 0)

__device__ __forceinline__ float4 ld4(const float* p) { return *reinterpret_cast<const float4*>(p); }

// ---------------- staging ----------------

__global__ __launch_bounds__(256) void k_stage(const float* __restrict__ b, const float* __restrict__ f,
                                               float* __restrict__ bs_c, float* __restrict__ fs_c) {
    int s = blockIdx.z;
    b += s * S_IN; f += s * S_IN; bs_c += s * S_BS; fs_c += s * S_BS;
    int c  = blockIdx.y;
    int rs = blockIdx.x * 256 + threadIdx.x;     // gridDim.x = 9
    int r = rs / GS, ss = rs % GS;
    int src = c * HW * HW + (2 * r) * HW + 2 * ss;
    bs_c[c * LL + rs] = b[src];
    fs_c[c * LL + rs] = f[src];
}

// partial ssq over 32 channels per block-row; ssq zeroed first (atomic accumulate)
__global__ __launch_bounds__(256) void k_ssq(const float* __restrict__ bs_c, float* __restrict__ ssq) {
    int s = blockIdx.z;
    bs_c += s * S_BS; ssq += (size_t)s * LL;
    int rs = blockIdx.x * 256 + threadIdx.x;
    int c0 = blockIdx.y * 32;
    float acc = 0.f;
    for (int c = c0; c < c0 + 32; ++c) { float v = bs_c[c * LL + rs]; acc += v * v; }
    atomicAdd(&ssq[rs], acc);
}

__global__ __launch_bounds__(256) void k_norm_mm(const float* __restrict__ ssq, const float* __restrict__ mk,
                                                 float* __restrict__ invn, float* __restrict__ mmv) {
    int sI = blockIdx.z;
    ssq += (size_t)sI * LL; mk += sI * S_MK; invn += (size_t)sI * LL; mmv += (size_t)sI * LL;
    int p = blockIdx.x * 256 + threadIdx.x;
    int ph = p / GS, pw = p % GS;
    float acc = EPSSUM;
    float msum = 0.f;
    for (int di = -1; di <= 1; ++di)
        for (int dj = -1; dj <= 1; ++dj) {
            int r = ph + di, s = pw + dj;
            if (r >= 0 && r < GS && s >= 0 && s < GS) {
                acc  += ssq[r * GS + s];
                msum += mk[(2 * r) * HW + 2 * s];
            }
        }
    invn[p] = 1.0f / sqrtf(acc);
    mmv[p]  = (msum / 9.0f == 1.0f) ? 1.0f : 0.0f;
}

// W2T[ck][p] = bf16( b[c, 2ph+dy-1, 2pw+dx-1] ), ck = c*16+dy*4+dx
__global__ __launch_bounds__(256) void k_w2T(const float* __restrict__ b, __hip_bfloat16* __restrict__ W2T) {
    int sI = blockIdx.z;
    b += sI * S_IN; W2T += sI * S_W2;
    int ck = blockIdx.y;
    int p  = blockIdx.x * 256 + threadIdx.x;     // gridDim.x = 9
    int c = ck >> 4, dy = (ck >> 2) & 3, dx = ck & 3;
    int ph = p / GS, pw = p % GS;
    int r = 2 * ph + dy - 1, s = 2 * pw + dx - 1;
    float v = 0.f;
    if (r >= 0 && r < HW && s >= 0 && s < HW) v = b[c * HW * HW + r * HW + s];
    W2T[(size_t)ck * LL + p] = __float2bfloat16(v);
}

// split fp32 [c][rs] -> transposed hi/lo bf16 [rs][c], into bufB scratch
__global__ __launch_bounds__(256) void k_split_T(const float* __restrict__ bs_c, const float* __restrict__ fs_c,
                                                 float* __restrict__ bufB) {
    __shared__ float tile[32][33];
    int z = blockIdx.z;
    int s = z >> 1, sel = z & 1;
    const float* X = (sel ? fs_c : bs_c) + s * S_BS;
    __hip_bfloat16* base = (__hip_bfloat16*)(bufB + s * S_BUF);
    __hip_bfloat16* hi = base + (size_t)sel * 2 * LL * CH;
    __hip_bfloat16* lo = hi + (size_t)LL * CH;
    int r0 = blockIdx.x * 32, c0 = blockIdx.y * 32;
    int tx = threadIdx.x & 31, ty = threadIdx.x >> 5;
#pragma unroll
    for (int j = 0; j < 4; ++j)
        tile[ty + 8 * j][tx] = X[(size_t)(c0 + ty + 8 * j) * LL + r0 + tx];
    __syncthreads();
#pragma unroll
    for (int j = 0; j < 4; ++j) {
        int rl = ty + 8 * j, cl = tx;
        float v = tile[cl][rl];
        __hip_bfloat16 h = __float2bfloat16(v);
        float resid = v - __bfloat162float(h);
        hi[(size_t)(r0 + rl) * CH + c0 + cl] = h;
        lo[(size_t)(r0 + rl) * CH + c0 + cl] = __float2bfloat16(resid);
    }
}

// ---------------- GEMM1 (split-bf16 MFMA): D = bs fs^T over channels ----------------
__global__ __launch_bounds__(256) void gemm1_mfma(const float* __restrict__ bufB, float* __restrict__ bufA) {
    __shared__ __hip_bfloat16 sAh[128 * 32];
    __shared__ __hip_bfloat16 sAl[128 * 32];
    __shared__ __hip_bfloat16 sBh[128 * 32];
    __shared__ __hip_bfloat16 sBl[128 * 32];
    int sI = blockIdx.z;
    const __hip_bfloat16* base = (const __hip_bfloat16*)(bufB + sI * S_BUF);
    const __hip_bfloat16* Ahi = base;
    const __hip_bfloat16* Alo = Ahi + (size_t)LL * CH;
    const __hip_bfloat16* Bhi = Alo + (size_t)LL * CH;
    const __hip_bfloat16* Blo = Bhi + (size_t)LL * CH;
    float* C = bufA + sI * S_BUF;

    int t = threadIdx.x, lane = t & 63, w = t >> 6;
    int wr = w >> 1, wc = w & 1;
    int m0 = blockIdx.y * 128, n0 = blockIdx.x * 128;

    float4v acc[4][4];
#pragma unroll
    for (int i = 0; i < 4; ++i)
#pragma unroll
        for (int j = 0; j < 4; ++j) acc[i][j] = (float4v){0.f, 0.f, 0.f, 0.f};

    for (int k0 = 0; k0 < 128; k0 += 32) {
#pragma unroll
        for (int it = 0; it < 2; ++it) {
            int chunk = it * 256 + w * 64 + lane;
            int row = chunk >> 2, ps = chunk & 3;
            int pd = ps ^ (row & 3);
            size_t ga = (size_t)(m0 + row) * 128 + k0 + pd * 8;
            size_t gb = (size_t)(n0 + row) * 128 + k0 + pd * 8;
            GLDS16(Ahi + ga, (char*)sAh + (size_t)chunk * 16);
            GLDS16(Alo + ga, (char*)sAl + (size_t)chunk * 16);
            GLDS16(Bhi + gb, (char*)sBh + (size_t)chunk * 16);
            GLDS16(Blo + gb, (char*)sBl + (size_t)chunk * 16);
        }
        __syncthreads();

        int lrow = lane & 15, part = lane >> 4;
        int sw = part ^ (lrow & 3);
        short8 ah[4], al[4], bh[4], bl[4];
#pragma unroll
        for (int i = 0; i < 4; ++i) {
            int slot = (wr * 64 + i * 16 + lrow) * 4 + sw;
            ah[i] = *reinterpret_cast<const short8*>(sAh + (size_t)slot * 8);
            al[i] = *reinterpret_cast<const short8*>(sAl + (size_t)slot * 8);
        }
#pragma unroll
        for (int j = 0; j < 4; ++j) {
            int slot = (wc * 64 + j * 16 + lrow) * 4 + sw;
            bh[j] = *reinterpret_cast<const short8*>(sBh + (size_t)slot * 8);
            bl[j] = *reinterpret_cast<const short8*>(sBl + (size_t)slot * 8);
        }
#pragma unroll
        for (int i = 0; i < 4; ++i)
#pragma unroll
            for (int j = 0; j < 4; ++j) {
                acc[i][j] = __builtin_amdgcn_mfma_f32_16x16x32_bf16(ah[i], bh[j], acc[i][j], 0, 0, 0);
                acc[i][j] = __builtin_amdgcn_mfma_f32_16x16x32_bf16(ah[i], bl[j], acc[i][j], 0, 0, 0);
                acc[i][j] = __builtin_amdgcn_mfma_f32_16x16x32_bf16(al[i], bh[j], acc[i][j], 0, 0, 0);
            }
        __syncthreads();
    }

    int col = lane & 15, rbase = (lane >> 4) * 4;
#pragma unroll
    for (int i = 0; i < 4; ++i)
#pragma unroll
        for (int j = 0; j < 4; ++j)
#pragma unroll
            for (int r = 0; r < 4; ++r) {
                int m = m0 + wr * 64 + i * 16 + rbase + r;
                int n = n0 + wc * 64 + j * 16 + col;
                C[(size_t)m * LL + n] = acc[i][j][r];
            }
}

// ---------------- GEMM2 (bf16 MFMA, bf16 output, TRANSPOSED result) ----------------
// Zt[ck][q] = sum_p W2T[ck][p] * attnT[q][p]. Proven R5 form: plain __syncthreads
// schedule (m97 structure) + XCD-chunked bijective tile swizzle (288 % 8 == 0).
// R6-R8 established: explicit dbuf / BK=64 / counted-vmcnt all regress here
// (inline-asm clobbers inflate VALU; drain scales with bytes, not events).
__global__ __launch_bounds__(256) void gemm2_mfma(const __hip_bfloat16* __restrict__ W2T_,
                                                  const __hip_bfloat16* __restrict__ attnT_,
                                                  float* __restrict__ bufA) {
    __shared__ __hip_bfloat16 As[128 * 32];
    __shared__ __hip_bfloat16 Bs[128 * 32];
    int sI = blockIdx.z;
    const __hip_bfloat16* A = W2T_ + sI * S_W2;        // [CKN][LL]
    const __hip_bfloat16* B = attnT_ + sI * S_AT;      // [LL][LL]
    __hip_bfloat16* C = (__hip_bfloat16*)(bufA + sI * S_BUF);   // Zt [CKN][LL]

    int t = threadIdx.x;
    int lane = t & 63, w = t >> 6;
    int wr = w >> 1, wc = w & 1;

    // bijective XCD swizzle (nwg = 288 = 8 * 36)
    int flat = blockIdx.y * 18 + blockIdx.x;
    int swz  = (flat & 7) * 36 + (flat >> 3);
    int by = swz / 18, bx = swz % 18;
    int m0 = by * 128, n0 = bx * 128;

    float4v acc[4][4];
#pragma unroll
    for (int i = 0; i < 4; ++i)
#pragma unroll
        for (int j = 0; j < 4; ++j) acc[i][j] = (float4v){0.f, 0.f, 0.f, 0.f};

    for (int k0 = 0; k0 < LL; k0 += 32) {
#pragma unroll
        for (int it = 0; it < 2; ++it) {
            int chunk = it * 256 + w * 64 + lane;
            int row = chunk >> 2, ps = chunk & 3;
            int pd = ps ^ (row & 3);
            const __hip_bfloat16* ga = A + (size_t)(m0 + row) * LL + k0 + pd * 8;
            const __hip_bfloat16* gb = B + (size_t)(n0 + row) * LL + k0 + pd * 8;
            GLDS16(ga, (char*)As + (size_t)chunk * 16);
            GLDS16(gb, (char*)Bs + (size_t)chunk * 16);
        }
        __syncthreads();

        int lrow = lane & 15, part = lane >> 4;
        int sw = part ^ (lrow & 3);
        short8 afrag[4], bfrag[4];
#pragma unroll
        for (int i = 0; i < 4; ++i) {
            int slot = (wr * 64 + i * 16 + lrow) * 4 + sw;
            afrag[i] = *reinterpret_cast<const short8*>(As + (size_t)slot * 8);
        }
#pragma unroll
        for (int j = 0; j < 4; ++j) {
            int slot = (wc * 64 + j * 16 + lrow) * 4 + sw;
            bfrag[j] = *reinterpret_cast<const short8*>(Bs + (size_t)slot * 8);
        }
#pragma unroll
        for (int i = 0; i < 4; ++i)
#pragma unroll
            for (int j = 0; j < 4; ++j)
                acc[i][j] = __builtin_amdgcn_mfma_f32_16x16x32_bf16(afrag[i], bfrag[j], acc[i][j], 0, 0, 0);
        __syncthreads();
    }

    int col = lane & 15, rbase = (lane >> 4) * 4;
#pragma unroll
    for (int i = 0; i < 4; ++i)
#pragma unroll
        for (int j = 0; j < 4; ++j)
#pragma unroll
            for (int r = 0; r < 4; ++r) {
                int m = m0 + wr * 64 + i * 16 + rbase + r;
                int n = n0 + wc * 64 + j * 16 + col;
                C[(size_t)m * LL + n] = __float2bfloat16(acc[i][j][r]);
            }
}

// ---------------- correlation assembly (float4-vectorized, 4 p's per block) ----------------
// yi[p][q] = invn[p] * sum_{valid di,dj} D[p+48di+dj][q+48di+dj]
// Batching 4 consecutive p per block: consecutive p's share 6 of 9 stencil rows, and
// the per-p block working set (~27KB) is L1-resident -> iterations 2-4 hit L1/L2.
// Arithmetic and order identical to the unbatched version (bit-exact).
__global__ __launch_bounds__(192) void k_corr_v4(const float* __restrict__ bufA, const float* __restrict__ invn,
                                                 float* __restrict__ bufB) {
    int sI = blockIdx.z;
    const float* D = bufA + sI * S_BUF;
    float* yi = bufB + sI * S_BUF;
    invn += (size_t)sI * LL;

    int qi = blockIdx.x * 192 + threadIdx.x;     // 0..575
    int q4 = qi * 4;
    int qh = q4 / GS, qw0 = q4 % GS;
    int p0 = blockIdx.y * 4;

    for (int pp = 0; pp < 4; ++pp) {
        int p = p0 + pp;
        int ph = p / GS, pw = p % GS;

        float4 acc = {0.f, 0.f, 0.f, 0.f};
#pragma unroll
        for (int di = -1; di <= 1; ++di) {
            int rp = ph + di, tq = qh + di;
            if (rp < 0 || rp >= GS || tq < 0 || tq >= GS) continue;
            int r0 = rp * GS + pw;           // = p + 48*di
            int c0 = tq * GS + qw0;          // = q4 + 48*di (4-aligned)
            // dj = 0
            {
                float4 Cc = ld4(D + (size_t)r0 * LL + c0);
                acc.x += Cc.x; acc.y += Cc.y; acc.z += Cc.z; acc.w += Cc.w;
            }
            // dj = -1 (row r0-1, cols c0-1..c0+2); valid iff pw>0; elem0 masked iff qw0==0
            if (pw > 0) {
                const float* rowm = D + (size_t)(r0 - 1) * LL;
                float4 L  = ld4(rowm + (qw0 > 0 ? c0 - 4 : c0));
                float4 Cm = ld4(rowm + c0);
                acc.x += (qw0 > 0 ? L.w : 0.f);
                acc.y += Cm.x; acc.z += Cm.y; acc.w += Cm.z;
            }
            // dj = +1 (row r0+1, cols c0+1..c0+4); valid iff pw<47; elem3 masked iff qw0==44
            if (pw < GS - 1) {
                const float* rowp = D + (size_t)(r0 + 1) * LL;
                float4 Cp = ld4(rowp + c0);
                float4 R  = ld4(rowp + (qw0 < GS - 4 ? c0 + 4 : c0));
                acc.x += Cp.y; acc.y += Cp.z; acc.z += Cp.w;
                acc.w += (qw0 < GS - 4 ? R.x : 0.f);
            }
        }
        float inv = invn[p];
        float4 outv = {inv * acc.x, inv * acc.y, inv * acc.z, inv * acc.w};
        *reinterpret_cast<float4*>(yi + (size_t)p * LL + q4) = outv;
    }
}

// ---------------- fuse1 (float4-vectorized, 4 a's per block): S1[a][b] = sum_d yi[a+d][b+d] ----------------
__global__ __launch_bounds__(192) void k_fuse1_v4(const float* __restrict__ bufB, float* __restrict__ bufA) {
    int sI = blockIdx.z;
    const float* yi = bufB + sI * S_BUF;
    float* S1 = bufA + sI * S_BUF;
    int bi = blockIdx.x * 192 + threadIdx.x;
    int b4 = bi * 4;
    int a0 = blockIdx.y * 4;

    for (int aa = 0; aa < 4; ++aa) {
        int a = a0 + aa;

        float4 acc = ld4(yi + (size_t)a * LL + b4);          // d = 0
        if (a > 0) {                                          // d = -1: cols b4-1..b4+2
            const float* rowm = yi + (size_t)(a - 1) * LL;
            float4 L  = ld4(rowm + (b4 > 0 ? b4 - 4 : b4));
            float4 Cm = ld4(rowm + b4);
            acc.x += (b4 > 0 ? L.w : 0.f);
            acc.y += Cm.x; acc.z += Cm.y; acc.w += Cm.z;
        }
        if (a < LL - 1) {                                     // d = +1: cols b4+1..b4+4
            const float* rowp = yi + (size_t)(a + 1) * LL;
            float4 Cp = ld4(rowp + b4);
            float4 R  = ld4(rowp + (b4 < LL - 4 ? b4 + 4 : b4));
            acc.x += Cp.y; acc.y += Cp.z; acc.z += Cp.w;
            acc.w += (b4 < LL - 4 ? R.x : 0.f);
        }
        *reinterpret_cast<float4*>(S1 + (size_t)a * LL + b4) = acc;
    }
}

__device__ __forceinline__ int gmap(int x) { int hi = x / GS; int lo = x - hi * GS; return lo * GS + hi; }

// fuse2 + softmax partials, 4-wide: within a 4-aligned q-quad qh is constant, and
// gmap(b0+e) = q + 48e (contiguous, 4-aligned) except at qh+e wrap -> scalar fallback.
__global__ __launch_bounds__(192) void k_fuse2_sm_v4(const float* __restrict__ bufA, const float* __restrict__ mmv,
                                                     float* __restrict__ bufB,
                                                     float* __restrict__ pmax, float* __restrict__ psum) {
    int sI = blockIdx.z;
    const float* S1 = bufA + sI * S_BUF;
    float* S2 = bufB + sI * S_BUF;
    mmv += (size_t)sI * LL; pmax += sI * S_PM; psum += sI * S_PM;
    int qi = blockIdx.x * 192 + threadIdx.x;   // 0..575
    int q4 = qi * 4;
    int qh = q4 / GS, qw0 = q4 % GS;
    int p0 = blockIdx.y * PCH2;
    float mxa[4], sma[4];
#pragma unroll
    for (int j = 0; j < 4; ++j) { mxa[j] = -1e30f; sma[j] = 0.f; }

    for (int i = 0; i < PCH2; ++i) {
        int p = p0 + i;
        int ph = p / GS, pw = p % GS;
        int a0 = pw * GS + ph;
        float sarr[4] = {0.f, 0.f, 0.f, 0.f};
#pragma unroll
        for (int e = -1; e <= 1; ++e) {
            int ae = a0 + e;
            if (ae < 0 || ae >= LL) continue;                 // uniform in block (p uniform)
            int Ar = gmap(ae);
            const float* Rw = S1 + (size_t)Ar * LL;
            int qe = qh + e;
            if (qe >= 0 && qe < GS) {                          // fast path: contiguous quad
                float4 v = ld4(Rw + q4 + 48 * e);
                sarr[0] += v.x; sarr[1] += v.y; sarr[2] += v.z; sarr[3] += v.w;
            } else {                                           // qh wrap: scalar gmap per element
#pragma unroll
                for (int j = 0; j < 4; ++j) {
                    int be = (qw0 + j) * GS + qh + e;
                    if (be >= 0 && be < LL) {
                        int bh = be / GS, bw = be % GS;
                        sarr[j] += Rw[bw * GS + bh];
                    }
                }
            }
        }
        float4 sv = {sarr[0], sarr[1], sarr[2], sarr[3]};
        *reinterpret_cast<float4*>(S2 + (size_t)p * LL + q4) = sv;
        float mv = mmv[p];
#pragma unroll
        for (int j = 0; j < 4; ++j) {
            float lg = (mv != 0.f) ? SCALE * sarr[j] : 0.f;
            float nm = fmaxf(mxa[j], lg);
            sma[j] = sma[j] * __expf(mxa[j] - nm) + __expf(lg - nm);
            mxa[j] = nm;
        }
    }
    float4 mo = {mxa[0], mxa[1], mxa[2], mxa[3]};
    float4 so = {sma[0], sma[1], sma[2], sma[3]};
    *reinterpret_cast<float4*>(pmax + blockIdx.y * LL + q4) = mo;
    *reinterpret_cast<float4*>(psum + blockIdx.y * LL + q4) = so;
}

// final softmax max/denominator: 4-way tree over 72 chunks, 64 q per block
__global__ __launch_bounds__(256) void k_sm2(const float* __restrict__ pmax, const float* __restrict__ psum,
                                             float* __restrict__ Mq, float* __restrict__ Dq) {
    __shared__ float red[4][64];
    int sI = blockIdx.z;
    pmax += sI * S_PM; psum += sI * S_PM; Mq += (size_t)sI * LL; Dq += (size_t)sI * LL;
    int t = threadIdx.x;
    int ql = t & 63, g = t >> 6;
    int q = blockIdx.x * 64 + ql;
    float mx = -1e30f;
    for (int ch = g * 18; ch < g * 18 + 18; ++ch) mx = fmaxf(mx, pmax[(size_t)ch * LL + q]);
    red[g][ql] = mx;
    __syncthreads();
    float mall = fmaxf(fmaxf(red[0][ql], red[1][ql]), fmaxf(red[2][ql], red[3][ql]));
    float sm = 0.f;
    for (int ch = g * 18; ch < g * 18 + 18; ++ch)
        sm += psum[(size_t)ch * LL + q] * __expf(pmax[(size_t)ch * LL + q] - mall);
    __syncthreads();
    red[g][ql] = sm;
    __syncthreads();
    if (g == 0) {
        Mq[q] = mall;
        Dq[q] = (red[0][ql] + red[1][ql]) + (red[2][ql] + red[3][ql]);
    }
}

// attnT[q][p] = bf16( mmv[p] * exp(10*S2[p][q] - Mq[q]) / Dq[q] ) via 32x32 LDS transpose
__global__ __launch_bounds__(256) void k_sm3T(const float* __restrict__ bufB, const float* __restrict__ mmv,
                                              const float* __restrict__ Mq, const float* __restrict__ Dq,
                                              __hip_bfloat16* __restrict__ attnT) {
    __shared__ float tile[32][33];
    int sI = blockIdx.z;
    const float* S2 = bufB + sI * S_BUF;
    mmv += (size_t)sI * LL; Mq += (size_t)sI * LL; Dq += (size_t)sI * LL; attnT += sI * S_AT;
    int tx = threadIdx.x & 31, ty = threadIdx.x >> 5;
    int p0 = blockIdx.y * 32, q0 = blockIdx.x * 32;
    int q = q0 + tx;
    float mq = Mq[q], dq = Dq[q];
#pragma unroll
    for (int j = 0; j < 4; ++j) {
        int p = p0 + ty + 8 * j;
        float v = S2[(size_t)p * LL + q];
        float attn = (mmv[p] != 0.f) ? __expf(SCALE * v - mq) / dq : 0.f;
        tile[ty + 8 * j][tx] = attn;
    }
    __syncthreads();
#pragma unroll
    for (int j = 0; j < 4; ++j) {
        int qq = q0 + ty + 8 * j;
        attnT[(size_t)qq * LL + p0 + tx] = __float2bfloat16(tile[tx][ty + 8 * j]);
    }
}

// ---------------- output assembly (reads bf16 Zt [CKN][LL]) ----------------
__global__ __launch_bounds__(256) void k_out(const float* __restrict__ bufA, float* __restrict__ out) {
    int sI = blockIdx.z;
    const __hip_bfloat16* Z = (const __hip_bfloat16*)(bufA + sI * S_BUF);   // Zt [CKN][LL]
    out += sI * S_IN;
    int c  = blockIdx.y;
    int yx = blockIdx.x * 256 + threadIdx.x;     // gridDim.x = 36
    int y = yx / HW, x = yx % HW;
    int u = y >> 1, a = y & 1, v = x >> 1, w = x & 1;
    int qh1 = u + a - 1, qh2 = u + a, qw1 = v + w - 1, qw2 = v + w;
    int cb = c * 16;
    float s = 0.f;
    if (qh1 >= 0) {
        if (qw1 >= 0)  s += __bfloat162float(Z[(size_t)(cb + (3 - a) * 4 + (3 - w)) * LL + qh1 * GS + qw1]);
        if (qw2 < GS)  s += __bfloat162float(Z[(size_t)(cb + (3 - a) * 4 + (1 - w)) * LL + qh1 * GS + qw2]);
    }
    if (qh2 < GS) {
        if (qw1 >= 0)  s += __bfloat162float(Z[(size_t)(cb + (1 - a) * 4 + (3 - w)) * LL + qh2 * GS + qw1]);
        if (qw2 < GS)  s += __bfloat162float(Z[(size_t)(cb + (1 - a) * 4 + (1 - w)) * LL + qh2 * GS + qw2]);
    }
    out[(size_t)c * HW * HW + yx] = 0.25f * s;
}

// ---------------- launch ----------------

extern "C" void kernel_launch(void* const* d_in, const int* in_sizes, int n_in,
                              void* d_out, int out_size, void* d_ws, size_t ws_size,
                              hipStream_t stream) {
    const float* b_all = (const float*)d_in[0];
    const float* f_all = (const float*)d_in[1];
    const float* m_all = (const float*)d_in[2];
    float* out = (float*)d_out;
    float* ws  = (float*)d_ws;

    const size_t perF = 2 * S_BS + 5 * (size_t)LL + 2 * S_PM + 2 * S_BUF + S_W2 / 2 + S_AT / 2;
    const size_t perB = perF * sizeof(float);
    int nb = (ws_size >= NS * perB) ? NS : ((ws_size >= 2 * perB) ? 2 : 1);

    size_t off = 0;
    float* bs_c = ws + off; off += nb * S_BS;
    float* fs_c = ws + off; off += nb * S_BS;
    float* ssq  = ws + off; off += nb * (size_t)LL;
    float* invn = ws + off; off += nb * (size_t)LL;
    float* mmv  = ws + off; off += nb * (size_t)LL;
    float* Mq   = ws + off; off += nb * (size_t)LL;
    float* Dq   = ws + off; off += nb * (size_t)LL;
    float* pmax = ws + off; off += nb * S_PM;
    float* psum = ws + off; off += nb * S_PM;
    float* bufA = ws + off; off += nb * S_BUF;   // D -> S1 -> Zt(bf16)
    float* bufB = ws + off; off += nb * S_BUF;   // (splits) -> yi -> S2
    __hip_bfloat16* W2T   = (__hip_bfloat16*)(ws + off); off += nb * S_W2 / 2;
    __hip_bfloat16* attnT = (__hip_bfloat16*)(ws + off); off += nb * S_AT / 2;

    for (int s0 = 0; s0 < NS; s0 += nb) {
        const float* b  = b_all + s0 * S_IN;
        const float* f  = f_all + s0 * S_IN;
        const float* mk = m_all + s0 * S_MK;
        float* outp = out + s0 * S_IN;

        hipMemsetAsync(ssq, 0, nb * LL * sizeof(float), stream);
        k_stage    <<<dim3(9, CH, nb), 256, 0, stream>>>(b, f, bs_c, fs_c);
        k_ssq      <<<dim3(9, 4, nb), 256, 0, stream>>>(bs_c, ssq);
        k_norm_mm  <<<dim3(9, 1, nb), 256, 0, stream>>>(ssq, mk, invn, mmv);
        k_w2T      <<<dim3(9, CKN, nb), 256, 0, stream>>>(b, W2T);
        k_split_T  <<<dim3(72, 4, 2 * nb), 256, 0, stream>>>(bs_c, fs_c, bufB);

        gemm1_mfma   <<<dim3(18, 18, nb), 256, 0, stream>>>(bufB, bufA);
        k_corr_v4    <<<dim3(3, LL / 4, nb), 192, 0, stream>>>(bufA, invn, bufB);
        k_fuse1_v4   <<<dim3(3, LL / 4, nb), 192, 0, stream>>>(bufB, bufA);
        k_fuse2_sm_v4<<<dim3(3, NCH2, nb), 192, 0, stream>>>(bufA, mmv, bufB, pmax, psum);

        k_sm2      <<<dim3(36, 1, nb), 256, 0, stream>>>(pmax, psum, Mq, Dq);
        k_sm3T     <<<dim3(72, 72, nb), 256, 0, stream>>>(bufB, mmv, Mq, Dq, attnT);

        gemm2_mfma <<<dim3(LL / 128, CKN / 128, nb), 256, 0, stream>>>(W2T, attnT, bufA);
        k_out      <<<dim3(36, CH, nb), 256, 0, stream>>>(bufA, outp);
    }
}

// Round 10
// 533.596 us; speedup vs baseline: 1.0255x; 1.0255x over previous
//
#include <hip/hip_runtime.h>
#include <hip/hip_bf16.h>
#include <math.h>

#define NS   4      // batch
#define CH   128    // channels
#define HW   96     // full-res H=W
#define GS   48     // half-res grid side
#define LL   2304   // GS*GS
#define CKN  2048   // CH*16 (4x4 taps)
#define SCALE 10.0f
#define EPSSUM 0.1152f  // 1152 * 1e-4
#define PCH2 32     // softmax p-chunk
#define NCH2 72     // 2304/32

// per-sample strides (elements)
#define S_IN  ((size_t)CH * HW * HW)   // b / f / out
#define S_MK  ((size_t)HW * HW)        // mask
#define S_BS  ((size_t)CH * LL)        // bs_c / fs_c
#define S_PM  ((size_t)NCH2 * LL)      // pmax / psum
#define S_BUF ((size_t)LL * LL)        // bufA / bufB (fp32)
#define S_W2  ((size_t)CKN * LL)       // W2T (bf16 elems)
#define S_AT  ((size_t)LL * LL)        // attnT (bf16 elems)

typedef __attribute__((ext_vector_type(8))) short short8;
typedef __attribute__((ext_vector_type(4))) float float4v;

#define GLDS16(gptr, lptr) \
    __builtin_amdgcn_global_load_lds((const __attribute__((address_space(1))) void*)(gptr), \
        (__attribute__((address_space(3))) void*)(lptr), 16, 0, 0)

__device__ __forceinline__ float4 ld4(const float* p) { return *reinterpret_cast<const float4*>(p); }

// ---------------- staging ----------------

__global__ __launch_bounds__(256) void k_stage(const float* __restrict__ b, const float* __restrict__ f,
                                               float* __restrict__ bs_c, float* __restrict__ fs_c) {
    int s = blockIdx.z;
    b += s * S_IN; f += s * S_IN; bs_c += s * S_BS; fs_c += s * S_BS;
    int c  = blockIdx.y;
    int rs = blockIdx.x * 256 + threadIdx.x;     // gridDim.x = 9
    int r = rs / GS, ss = rs % GS;
    int src = c * HW * HW + (2 * r) * HW + 2 * ss;
    bs_c[c * LL + rs] = b[src];
    fs_c[c * LL + rs] = f[src];
}

// partial ssq over 32 channels per block-row; ssq zeroed first (atomic accumulate)
__global__ __launch_bounds__(256) void k_ssq(const float* __restrict__ bs_c, float* __restrict__ ssq) {
    int s = blockIdx.z;
    bs_c += s * S_BS; ssq += (size_t)s * LL;
    int rs = blockIdx.x * 256 + threadIdx.x;
    int c0 = blockIdx.y * 32;
    float acc = 0.f;
    for (int c = c0; c < c0 + 32; ++c) { float v = bs_c[c * LL + rs]; acc += v * v; }
    atomicAdd(&ssq[rs], acc);
}

__global__ __launch_bounds__(256) void k_norm_mm(const float* __restrict__ ssq, const float* __restrict__ mk,
                                                 float* __restrict__ invn, float* __restrict__ mmv) {
    int sI = blockIdx.z;
    ssq += (size_t)sI * LL; mk += sI * S_MK; invn += (size_t)sI * LL; mmv += (size_t)sI * LL;
    int p = blockIdx.x * 256 + threadIdx.x;
    int ph = p / GS, pw = p % GS;
    float acc = EPSSUM;
    float msum = 0.f;
    for (int di = -1; di <= 1; ++di)
        for (int dj = -1; dj <= 1; ++dj) {
            int r = ph + di, s = pw + dj;
            if (r >= 0 && r < GS && s >= 0 && s < GS) {
                acc  += ssq[r * GS + s];
                msum += mk[(2 * r) * HW + 2 * s];
            }
        }
    invn[p] = 1.0f / sqrtf(acc);
    mmv[p]  = (msum / 9.0f == 1.0f) ? 1.0f : 0.0f;
}

// W2T[ck][p] = bf16( b[c, 2ph+dy-1, 2pw+dx-1] ), ck = c*16+dy*4+dx
__global__ __launch_bounds__(256) void k_w2T(const float* __restrict__ b, __hip_bfloat16* __restrict__ W2T) {
    int sI = blockIdx.z;
    b += sI * S_IN; W2T += sI * S_W2;
    int ck = blockIdx.y;
    int p  = blockIdx.x * 256 + threadIdx.x;     // gridDim.x = 9
    int c = ck >> 4, dy = (ck >> 2) & 3, dx = ck & 3;
    int ph = p / GS, pw = p % GS;
    int r = 2 * ph + dy - 1, s = 2 * pw + dx - 1;
    float v = 0.f;
    if (r >= 0 && r < HW && s >= 0 && s < HW) v = b[c * HW * HW + r * HW + s];
    W2T[(size_t)ck * LL + p] = __float2bfloat16(v);
}

// split fp32 [c][rs] -> transposed hi/lo bf16 [rs][c], into bufB scratch
__global__ __launch_bounds__(256) void k_split_T(const float* __restrict__ bs_c, const float* __restrict__ fs_c,
                                                 float* __restrict__ bufB) {
    __shared__ float tile[32][33];
    int z = blockIdx.z;
    int s = z >> 1, sel = z & 1;
    const float* X = (sel ? fs_c : bs_c) + s * S_BS;
    __hip_bfloat16* base = (__hip_bfloat16*)(bufB + s * S_BUF);
    __hip_bfloat16* hi = base + (size_t)sel * 2 * LL * CH;
    __hip_bfloat16* lo = hi + (size_t)LL * CH;
    int r0 = blockIdx.x * 32, c0 = blockIdx.y * 32;
    int tx = threadIdx.x & 31, ty = threadIdx.x >> 5;
#pragma unroll
    for (int j = 0; j < 4; ++j)
        tile[ty + 8 * j][tx] = X[(size_t)(c0 + ty + 8 * j) * LL + r0 + tx];
    __syncthreads();
#pragma unroll
    for (int j = 0; j < 4; ++j) {
        int rl = ty + 8 * j, cl = tx;
        float v = tile[cl][rl];
        __hip_bfloat16 h = __float2bfloat16(v);
        float resid = v - __bfloat162float(h);
        hi[(size_t)(r0 + rl) * CH + c0 + cl] = h;
        lo[(size_t)(r0 + rl) * CH + c0 + cl] = __float2bfloat16(resid);
    }
}

// ---------------- GEMM1 (split-bf16 MFMA): D = bs fs^T over channels ----------------
__global__ __launch_bounds__(256) void gemm1_mfma(const float* __restrict__ bufB, float* __restrict__ bufA) {
    __shared__ __hip_bfloat16 sAh[128 * 32];
    __shared__ __hip_bfloat16 sAl[128 * 32];
    __shared__ __hip_bfloat16 sBh[128 * 32];
    __shared__ __hip_bfloat16 sBl[128 * 32];
    int sI = blockIdx.z;
    const __hip_bfloat16* base = (const __hip_bfloat16*)(bufB + sI * S_BUF);
    const __hip_bfloat16* Ahi = base;
    const __hip_bfloat16* Alo = Ahi + (size_t)LL * CH;
    const __hip_bfloat16* Bhi = Alo + (size_t)LL * CH;
    const __hip_bfloat16* Blo = Bhi + (size_t)LL * CH;
    float* C = bufA + sI * S_BUF;

    int t = threadIdx.x, lane = t & 63, w = t >> 6;
    int wr = w >> 1, wc = w & 1;
    int m0 = blockIdx.y * 128, n0 = blockIdx.x * 128;

    float4v acc[4][4];
#pragma unroll
    for (int i = 0; i < 4; ++i)
#pragma unroll
        for (int j = 0; j < 4; ++j) acc[i][j] = (float4v){0.f, 0.f, 0.f, 0.f};

    for (int k0 = 0; k0 < 128; k0 += 32) {
#pragma unroll
        for (int it = 0; it < 2; ++it) {
            int chunk = it * 256 + w * 64 + lane;
            int row = chunk >> 2, ps = chunk & 3;
            int pd = ps ^ (row & 3);
            size_t ga = (size_t)(m0 + row) * 128 + k0 + pd * 8;
            size_t gb = (size_t)(n0 + row) * 128 + k0 + pd * 8;
            GLDS16(Ahi + ga, (char*)sAh + (size_t)chunk * 16);
            GLDS16(Alo + ga, (char*)sAl + (size_t)chunk * 16);
            GLDS16(Bhi + gb, (char*)sBh + (size_t)chunk * 16);
            GLDS16(Blo + gb, (char*)sBl + (size_t)chunk * 16);
        }
        __syncthreads();

        int lrow = lane & 15, part = lane >> 4;
        int sw = part ^ (lrow & 3);
        short8 ah[4], al[4], bh[4], bl[4];
#pragma unroll
        for (int i = 0; i < 4; ++i) {
            int slot = (wr * 64 + i * 16 + lrow) * 4 + sw;
            ah[i] = *reinterpret_cast<const short8*>(sAh + (size_t)slot * 8);
            al[i] = *reinterpret_cast<const short8*>(sAl + (size_t)slot * 8);
        }
#pragma unroll
        for (int j = 0; j < 4; ++j) {
            int slot = (wc * 64 + j * 16 + lrow) * 4 + sw;
            bh[j] = *reinterpret_cast<const short8*>(sBh + (size_t)slot * 8);
            bl[j] = *reinterpret_cast<const short8*>(sBl + (size_t)slot * 8);
        }
#pragma unroll
        for (int i = 0; i < 4; ++i)
#pragma unroll
            for (int j = 0; j < 4; ++j) {
                acc[i][j] = __builtin_amdgcn_mfma_f32_16x16x32_bf16(ah[i], bh[j], acc[i][j], 0, 0, 0);
                acc[i][j] = __builtin_amdgcn_mfma_f32_16x16x32_bf16(ah[i], bl[j], acc[i][j], 0, 0, 0);
                acc[i][j] = __builtin_amdgcn_mfma_f32_16x16x32_bf16(al[i], bh[j], acc[i][j], 0, 0, 0);
            }
        __syncthreads();
    }

    int col = lane & 15, rbase = (lane >> 4) * 4;
#pragma unroll
    for (int i = 0; i < 4; ++i)
#pragma unroll
        for (int j = 0; j < 4; ++j)
#pragma unroll
            for (int r = 0; r < 4; ++r) {
                int m = m0 + wr * 64 + i * 16 + rbase + r;
                int n = n0 + wc * 64 + j * 16 + col;
                C[(size_t)m * LL + n] = acc[i][j][r];
            }
}

// ---------------- GEMM2 (bf16 MFMA, bf16 output, TRANSPOSED result) ----------------
// Zt[ck][q] = sum_p W2T[ck][p] * attnT[q][p]. Proven R5 form: plain __syncthreads
// schedule (m97 structure) + XCD-chunked bijective tile swizzle (288 % 8 == 0).
// R6-R8 established: explicit dbuf / BK=64 / counted-vmcnt all regress here.
// __launch_bounds__(256,3): request >=3 waves/EU (3 blocks/CU); caps VGPR at 170
// (arch 76 + 64 AGPR ~ 140-144 fits, no spill) — probes whether residency, not
// schedule, limits the 25% occupancy.
__global__ __launch_bounds__(256, 3) void gemm2_mfma(const __hip_bfloat16* __restrict__ W2T_,
                                                     const __hip_bfloat16* __restrict__ attnT_,
                                                     float* __restrict__ bufA) {
    __shared__ __hip_bfloat16 As[128 * 32];
    __shared__ __hip_bfloat16 Bs[128 * 32];
    int sI = blockIdx.z;
    const __hip_bfloat16* A = W2T_ + sI * S_W2;        // [CKN][LL]
    const __hip_bfloat16* B = attnT_ + sI * S_AT;      // [LL][LL]
    __hip_bfloat16* C = (__hip_bfloat16*)(bufA + sI * S_BUF);   // Zt [CKN][LL]

    int t = threadIdx.x;
    int lane = t & 63, w = t >> 6;
    int wr = w >> 1, wc = w & 1;

    // bijective XCD swizzle (nwg = 288 = 8 * 36)
    int flat = blockIdx.y * 18 + blockIdx.x;
    int swz  = (flat & 7) * 36 + (flat >> 3);
    int by = swz / 18, bx = swz % 18;
    int m0 = by * 128, n0 = bx * 128;

    float4v acc[4][4];
#pragma unroll
    for (int i = 0; i < 4; ++i)
#pragma unroll
        for (int j = 0; j < 4; ++j) acc[i][j] = (float4v){0.f, 0.f, 0.f, 0.f};

    for (int k0 = 0; k0 < LL; k0 += 32) {
#pragma unroll
        for (int it = 0; it < 2; ++it) {
            int chunk = it * 256 + w * 64 + lane;
            int row = chunk >> 2, ps = chunk & 3;
            int pd = ps ^ (row & 3);
            const __hip_bfloat16* ga = A + (size_t)(m0 + row) * LL + k0 + pd * 8;
            const __hip_bfloat16* gb = B + (size_t)(n0 + row) * LL + k0 + pd * 8;
            GLDS16(ga, (char*)As + (size_t)chunk * 16);
            GLDS16(gb, (char*)Bs + (size_t)chunk * 16);
        }
        __syncthreads();

        int lrow = lane & 15, part = lane >> 4;
        int sw = part ^ (lrow & 3);
        short8 afrag[4], bfrag[4];
#pragma unroll
        for (int i = 0; i < 4; ++i) {
            int slot = (wr * 64 + i * 16 + lrow) * 4 + sw;
            afrag[i] = *reinterpret_cast<const short8*>(As + (size_t)slot * 8);
        }
#pragma unroll
        for (int j = 0; j < 4; ++j) {
            int slot = (wc * 64 + j * 16 + lrow) * 4 + sw;
            bfrag[j] = *reinterpret_cast<const short8*>(Bs + (size_t)slot * 8);
        }
#pragma unroll
        for (int i = 0; i < 4; ++i)
#pragma unroll
            for (int j = 0; j < 4; ++j)
                acc[i][j] = __builtin_amdgcn_mfma_f32_16x16x32_bf16(afrag[i], bfrag[j], acc[i][j], 0, 0, 0);
        __syncthreads();
    }

    int col = lane & 15, rbase = (lane >> 4) * 4;
#pragma unroll
    for (int i = 0; i < 4; ++i)
#pragma unroll
        for (int j = 0; j < 4; ++j)
#pragma unroll
            for (int r = 0; r < 4; ++r) {
                int m = m0 + wr * 64 + i * 16 + rbase + r;
                int n = n0 + wc * 64 + j * 16 + col;
                C[(size_t)m * LL + n] = __float2bfloat16(acc[i][j][r]);
            }
}

// ---------------- correlation assembly (float4-vectorized, unbatched: max TLP) ----------------
// yi[p][q] = invn[p] * sum_{valid di,dj} D[p+48di+dj][q+48di+dj]
// R3/R9 lesson: this latency-bound stencil lives off massive TLP (27.6k blocks);
// any batching/fusion that cuts block count regresses.
__global__ __launch_bounds__(192) void k_corr_v4(const float* __restrict__ bufA, const float* __restrict__ invn,
                                                 float* __restrict__ bufB) {
    int sI = blockIdx.z;
    const float* D = bufA + sI * S_BUF;
    float* yi = bufB + sI * S_BUF;
    invn += (size_t)sI * LL;

    int p  = blockIdx.y;
    int qi = blockIdx.x * 192 + threadIdx.x;     // 0..575
    int q4 = qi * 4;
    int qh = q4 / GS, qw0 = q4 % GS;
    int ph = p / GS, pw = p % GS;

    float4 acc = {0.f, 0.f, 0.f, 0.f};
#pragma unroll
    for (int di = -1; di <= 1; ++di) {
        int rp = ph + di, tq = qh + di;
        if (rp < 0 || rp >= GS || tq < 0 || tq >= GS) continue;
        int r0 = rp * GS + pw;           // = p + 48*di
        int c0 = tq * GS + qw0;          // = q4 + 48*di (4-aligned)
        // dj = 0
        {
            float4 Cc = ld4(D + (size_t)r0 * LL + c0);
            acc.x += Cc.x; acc.y += Cc.y; acc.z += Cc.z; acc.w += Cc.w;
        }
        // dj = -1 (row r0-1, cols c0-1..c0+2); valid iff pw>0; elem0 masked iff qw0==0
        if (pw > 0) {
            const float* rowm = D + (size_t)(r0 - 1) * LL;
            float4 L  = ld4(rowm + (qw0 > 0 ? c0 - 4 : c0));
            float4 Cm = ld4(rowm + c0);
            acc.x += (qw0 > 0 ? L.w : 0.f);
            acc.y += Cm.x; acc.z += Cm.y; acc.w += Cm.z;
        }
        // dj = +1 (row r0+1, cols c0+1..c0+4); valid iff pw<47; elem3 masked iff qw0==44
        if (pw < GS - 1) {
            const float* rowp = D + (size_t)(r0 + 1) * LL;
            float4 Cp = ld4(rowp + c0);
            float4 R  = ld4(rowp + (qw0 < GS - 4 ? c0 + 4 : c0));
            acc.x += Cp.y; acc.y += Cp.z; acc.z += Cp.w;
            acc.w += (qw0 < GS - 4 ? R.x : 0.f);
        }
    }
    float inv = invn[p];
    float4 outv = {inv * acc.x, inv * acc.y, inv * acc.z, inv * acc.w};
    *reinterpret_cast<float4*>(yi + (size_t)p * LL + q4) = outv;
}

// ---------------- fuse1 (float4-vectorized, unbatched): S1[a][b] = sum_d yi[a+d][b+d] ----------------
__global__ __launch_bounds__(192) void k_fuse1_v4(const float* __restrict__ bufB, float* __restrict__ bufA) {
    int sI = blockIdx.z;
    const float* yi = bufB + sI * S_BUF;
    float* S1 = bufA + sI * S_BUF;
    int a  = blockIdx.y;
    int bi = blockIdx.x * 192 + threadIdx.x;
    int b4 = bi * 4;

    float4 acc = ld4(yi + (size_t)a * LL + b4);          // d = 0
    if (a > 0) {                                          // d = -1: cols b4-1..b4+2
        const float* rowm = yi + (size_t)(a - 1) * LL;
        float4 L  = ld4(rowm + (b4 > 0 ? b4 - 4 : b4));
        float4 Cm = ld4(rowm + b4);
        acc.x += (b4 > 0 ? L.w : 0.f);
        acc.y += Cm.x; acc.z += Cm.y; acc.w += Cm.z;
    }
    if (a < LL - 1) {                                     // d = +1: cols b4+1..b4+4
        const float* rowp = yi + (size_t)(a + 1) * LL;
        float4 Cp = ld4(rowp + b4);
        float4 R  = ld4(rowp + (b4 < LL - 4 ? b4 + 4 : b4));
        acc.x += Cp.y; acc.y += Cp.z; acc.z += Cp.w;
        acc.w += (b4 < LL - 4 ? R.x : 0.f);
    }
    *reinterpret_cast<float4*>(S1 + (size_t)a * LL + b4) = acc;
}

__device__ __forceinline__ int gmap(int x) { int hi = x / GS; int lo = x - hi * GS; return lo * GS + hi; }

// fuse2 + softmax partials, 4-wide: within a 4-aligned q-quad qh is constant, and
// gmap(b0+e) = q + 48e (contiguous, 4-aligned) except at qh+e wrap -> scalar fallback.
__global__ __launch_bounds__(192) void k_fuse2_sm_v4(const float* __restrict__ bufA, const float* __restrict__ mmv,
                                                     float* __restrict__ bufB,
                                                     float* __restrict__ pmax, float* __restrict__ psum) {
    int sI = blockIdx.z;
    const float* S1 = bufA + sI * S_BUF;
    float* S2 = bufB + sI * S_BUF;
    mmv += (size_t)sI * LL; pmax += sI * S_PM; psum += sI * S_PM;
    int qi = blockIdx.x * 192 + threadIdx.x;   // 0..575
    int q4 = qi * 4;
    int qh = q4 / GS, qw0 = q4 % GS;
    int p0 = blockIdx.y * PCH2;
    float mxa[4], sma[4];
#pragma unroll
    for (int j = 0; j < 4; ++j) { mxa[j] = -1e30f; sma[j] = 0.f; }

    for (int i = 0; i < PCH2; ++i) {
        int p = p0 + i;
        int ph = p / GS, pw = p % GS;
        int a0 = pw * GS + ph;
        float sarr[4] = {0.f, 0.f, 0.f, 0.f};
#pragma unroll
        for (int e = -1; e <= 1; ++e) {
            int ae = a0 + e;
            if (ae < 0 || ae >= LL) continue;                 // uniform in block (p uniform)
            int Ar = gmap(ae);
            const float* Rw = S1 + (size_t)Ar * LL;
            int qe = qh + e;
            if (qe >= 0 && qe < GS) {                          // fast path: contiguous quad
                float4 v = ld4(Rw + q4 + 48 * e);
                sarr[0] += v.x; sarr[1] += v.y; sarr[2] += v.z; sarr[3] += v.w;
            } else {                                           // qh wrap: scalar gmap per element
#pragma unroll
                for (int j = 0; j < 4; ++j) {
                    int be = (qw0 + j) * GS + qh + e;
                    if (be >= 0 && be < LL) {
                        int bh = be / GS, bw = be % GS;
                        sarr[j] += Rw[bw * GS + bh];
                    }
                }
            }
        }
        float4 sv = {sarr[0], sarr[1], sarr[2], sarr[3]};
        *reinterpret_cast<float4*>(S2 + (size_t)p * LL + q4) = sv;
        float mv = mmv[p];
#pragma unroll
        for (int j = 0; j < 4; ++j) {
            float lg = (mv != 0.f) ? SCALE * sarr[j] : 0.f;
            float nm = fmaxf(mxa[j], lg);
            sma[j] = sma[j] * __expf(mxa[j] - nm) + __expf(lg - nm);
            mxa[j] = nm;
        }
    }
    float4 mo = {mxa[0], mxa[1], mxa[2], mxa[3]};
    float4 so = {sma[0], sma[1], sma[2], sma[3]};
    *reinterpret_cast<float4*>(pmax + blockIdx.y * LL + q4) = mo;
    *reinterpret_cast<float4*>(psum + blockIdx.y * LL + q4) = so;
}

// final softmax max/denominator: 4-way tree over 72 chunks, 64 q per block
__global__ __launch_bounds__(256) void k_sm2(const float* __restrict__ pmax, const float* __restrict__ psum,
                                             float* __restrict__ Mq, float* __restrict__ Dq) {
    __shared__ float red[4][64];
    int sI = blockIdx.z;
    pmax += sI * S_PM; psum += sI * S_PM; Mq += (size_t)sI * LL; Dq += (size_t)sI * LL;
    int t = threadIdx.x;
    int ql = t & 63, g = t >> 6;
    int q = blockIdx.x * 64 + ql;
    float mx = -1e30f;
    for (int ch = g * 18; ch < g * 18 + 18; ++ch) mx = fmaxf(mx, pmax[(size_t)ch * LL + q]);
    red[g][ql] = mx;
    __syncthreads();
    float mall = fmaxf(fmaxf(red[0][ql], red[1][ql]), fmaxf(red[2][ql], red[3][ql]));
    float sm = 0.f;
    for (int ch = g * 18; ch < g * 18 + 18; ++ch)
        sm += psum[(size_t)ch * LL + q] * __expf(pmax[(size_t)ch * LL + q] - mall);
    __syncthreads();
    red[g][ql] = sm;
    __syncthreads();
    if (g == 0) {
        Mq[q] = mall;
        Dq[q] = (red[0][ql] + red[1][ql]) + (red[2][ql] + red[3][ql]);
    }
}

// attnT[q][p] = bf16( mmv[p] * exp(10*S2[p][q] - Mq[q]) / Dq[q] ) via 32x32 LDS transpose
__global__ __launch_bounds__(256) void k_sm3T(const float* __restrict__ bufB, const float* __restrict__ mmv,
                                              const float* __restrict__ Mq, const float* __restrict__ Dq,
                                              __hip_bfloat16* __restrict__ attnT) {
    __shared__ float tile[32][33];
    int sI = blockIdx.z;
    const float* S2 = bufB + sI * S_BUF;
    mmv += (size_t)sI * LL; Mq += (size_t)sI * LL; Dq += (size_t)sI * LL; attnT += sI * S_AT;
    int tx = threadIdx.x & 31, ty = threadIdx.x >> 5;
    int p0 = blockIdx.y * 32, q0 = blockIdx.x * 32;
    int q = q0 + tx;
    float mq = Mq[q], dq = Dq[q];
#pragma unroll
    for (int j = 0; j < 4; ++j) {
        int p = p0 + ty + 8 * j;
        float v = S2[(size_t)p * LL + q];
        float attn = (mmv[p] != 0.f) ? __expf(SCALE * v - mq) / dq : 0.f;
        tile[ty + 8 * j][tx] = attn;
    }
    __syncthreads();
#pragma unroll
    for (int j = 0; j < 4; ++j) {
        int qq = q0 + ty + 8 * j;
        attnT[(size_t)qq * LL + p0 + tx] = __float2bfloat16(tile[tx][ty + 8 * j]);
    }
}

// ---------------- output assembly (reads bf16 Zt [CKN][LL]) ----------------
__global__ __launch_bounds__(256) void k_out(const float* __restrict__ bufA, float* __restrict__ out) {
    int sI = blockIdx.z;
    const __hip_bfloat16* Z = (const __hip_bfloat16*)(bufA + sI * S_BUF);   // Zt [CKN][LL]
    out += sI * S_IN;
    int c  = blockIdx.y;
    int yx = blockIdx.x * 256 + threadIdx.x;     // gridDim.x = 36
    int y = yx / HW, x = yx % HW;
    int u = y >> 1, a = y & 1, v = x >> 1, w = x & 1;
    int qh1 = u + a - 1, qh2 = u + a, qw1 = v + w - 1, qw2 = v + w;
    int cb = c * 16;
    float s = 0.f;
    if (qh1 >= 0) {
        if (qw1 >= 0)  s += __bfloat162float(Z[(size_t)(cb + (3 - a) * 4 + (3 - w)) * LL + qh1 * GS + qw1]);
        if (qw2 < GS)  s += __bfloat162float(Z[(size_t)(cb + (3 - a) * 4 + (1 - w)) * LL + qh1 * GS + qw2]);
    }
    if (qh2 < GS) {
        if (qw1 >= 0)  s += __bfloat162float(Z[(size_t)(cb + (1 - a) * 4 + (3 - w)) * LL + qh2 * GS + qw1]);
        if (qw2 < GS)  s += __bfloat162float(Z[(size_t)(cb + (1 - a) * 4 + (1 - w)) * LL + qh2 * GS + qw2]);
    }
    out[(size_t)c * HW * HW + yx] = 0.25f * s;
}

// ---------------- launch ----------------

extern "C" void kernel_launch(void* const* d_in, const int* in_sizes, int n_in,
                              void* d_out, int out_size, void* d_ws, size_t ws_size,
                              hipStream_t stream) {
    const float* b_all = (const float*)d_in[0];
    const float* f_all = (const float*)d_in[1];
    const float* m_all = (const float*)d_in[2];
    float* out = (float*)d_out;
    float* ws  = (float*)d_ws;

    const size_t perF = 2 * S_BS + 5 * (size_t)LL + 2 * S_PM + 2 * S_BUF + S_W2 / 2 + S_AT / 2;
    const size_t perB = perF * sizeof(float);
    int nb = (ws_size >= NS * perB) ? NS : ((ws_size >= 2 * perB) ? 2 : 1);

    size_t off = 0;
    float* bs_c = ws + off; off += nb * S_BS;
    float* fs_c = ws + off; off += nb * S_BS;
    float* ssq  = ws + off; off += nb * (size_t)LL;
    float* invn = ws + off; off += nb * (size_t)LL;
    float* mmv  = ws + off; off += nb * (size_t)LL;
    float* Mq   = ws + off; off += nb * (size_t)LL;
    float* Dq   = ws + off; off += nb * (size_t)LL;
    float* pmax = ws + off; off += nb * S_PM;
    float* psum = ws + off; off += nb * S_PM;
    float* bufA = ws + off; off += nb * S_BUF;   // D -> S1 -> Zt(bf16)
    float* bufB = ws + off; off += nb * S_BUF;   // (splits) -> yi -> S2
    __hip_bfloat16* W2T   = (__hip_bfloat16*)(ws + off); off += nb * S_W2 / 2;
    __hip_bfloat16* attnT = (__hip_bfloat16*)(ws + off); off += nb * S_AT / 2;

    for (int s0 = 0; s0 < NS; s0 += nb) {
        const float* b  = b_all + s0 * S_IN;
        const float* f  = f_all + s0 * S_IN;
        const float* mk = m_all + s0 * S_MK;
        float* outp = out + s0 * S_IN;

        hipMemsetAsync(ssq, 0, nb * LL * sizeof(float), stream);
        k_stage    <<<dim3(9, CH, nb), 256, 0, stream>>>(b, f, bs_c, fs_c);
        k_ssq      <<<dim3(9, 4, nb), 256, 0, stream>>>(bs_c, ssq);
        k_norm_mm  <<<dim3(9, 1, nb), 256, 0, stream>>>(ssq, mk, invn, mmv);
        k_w2T      <<<dim3(9, CKN, nb), 256, 0, stream>>>(b, W2T);
        k_split_T  <<<dim3(72, 4, 2 * nb), 256, 0, stream>>>(bs_c, fs_c, bufB);

        gemm1_mfma   <<<dim3(18, 18, nb), 256, 0, stream>>>(bufB, bufA);
        k_corr_v4    <<<dim3(3, LL, nb), 192, 0, stream>>>(bufA, invn, bufB);
        k_fuse1_v4   <<<dim3(3, LL, nb), 192, 0, stream>>>(bufB, bufA);
        k_fuse2_sm_v4<<<dim3(3, NCH2, nb), 192, 0, stream>>>(bufA, mmv, bufB, pmax, psum);

        k_sm2      <<<dim3(36, 1, nb), 256, 0, stream>>>(pmax, psum, Mq, Dq);
        k_sm3T     <<<dim3(72, 72, nb), 256, 0, stream>>>(bufB, mmv, Mq, Dq, attnT);

        gemm2_mfma <<<dim3(LL / 128, CKN / 128, nb), 256, 0, stream>>>(W2T, attnT, bufA);
        k_out      <<<dim3(36, CH, nb), 256, 0, stream>>>(bufA, outp);
    }
}

// Round 11
// 522.764 us; speedup vs baseline: 1.0467x; 1.0207x over previous
//
#include <hip/hip_runtime.h>
#include <hip/hip_bf16.h>
#include <math.h>

#define NS   4      // batch
#define CH   128    // channels
#define HW   96     // full-res H=W
#define GS   48     // half-res grid side
#define LL   2304   // GS*GS
#define CKN  2048   // CH*16 (4x4 taps)
#define SCALE 10.0f
#define EPSSUM 0.1152f  // 1152 * 1e-4
#define PCH2 32     // softmax p-chunk
#define NCH2 72     // 2304/32

// per-sample strides (elements)
#define S_IN  ((size_t)CH * HW * HW)   // b / f / out
#define S_MK  ((size_t)HW * HW)        // mask
#define S_PM  ((size_t)NCH2 * LL)      // pmax / psum
#define S_BUF ((size_t)LL * LL)        // bufA / bufB (fp32)
#define S_W2  ((size_t)CKN * LL)       // W2T (bf16 elems)
#define S_AT  ((size_t)LL * LL)        // attnT (bf16 elems)

typedef __attribute__((ext_vector_type(8))) short short8;
typedef __attribute__((ext_vector_type(4))) float float4v;

#define GLDS16(gptr, lptr) \
    __builtin_amdgcn_global_load_lds((const __attribute__((address_space(1))) void*)(gptr), \
        (__attribute__((address_space(3))) void*)(lptr), 16, 0, 0)

__device__ __forceinline__ float4 ld4(const float* p) { return *reinterpret_cast<const float4*>(p); }

// ---------------- fused staging: subsample + ssq + transposed hi/lo bf16 split ----------------
// Replaces k_stage + k_ssq + k_split_T (R11): reads b/f directly (stride-2 gather),
// 32x32 LDS transpose, ssq partial summed in the SAME c-order + 4-way atomic structure
// as the old k_ssq (bit-identical invn), writes hi/lo bf16 [rs][c] splits into bufB.
// bs_c/fs_c buffers eliminated (-23MB round-trip, -2 launches).
__global__ __launch_bounds__(256) void k_stage_split(const float* __restrict__ b, const float* __restrict__ f,
                                                     float* __restrict__ ssq, float* __restrict__ bufB) {
    __shared__ float tile[32][33];
    int z = blockIdx.z;
    int s = z >> 1, sel = z & 1;
    const float* X = (sel ? f : b) + s * S_IN;
    __hip_bfloat16* base = (__hip_bfloat16*)(bufB + s * S_BUF);
    __hip_bfloat16* hi = base + (size_t)sel * 2 * LL * CH;
    __hip_bfloat16* lo = hi + (size_t)LL * CH;
    int r0 = blockIdx.x * 32, c0 = blockIdx.y * 32;   // r0 over rs (LL), c0 over CH
    int tx = threadIdx.x & 31, ty = threadIdx.x >> 5;

    // load tile[c_local][rs_local] from subsampled source
#pragma unroll
    for (int j = 0; j < 4; ++j) {
        int c  = c0 + ty + 8 * j;
        int rs = r0 + tx;
        int r = rs / GS, ss_ = rs % GS;
        tile[ty + 8 * j][tx] = X[(size_t)c * HW * HW + (2 * r) * HW + 2 * ss_];
    }
    __syncthreads();

    // ssq partial (b only): thread tx owns rs = r0+tx; sum channels c0..c0+31 IN ORDER
    // (matches old k_ssq's register-accumulate order; 4 c-tile blocks atomic like old 4 y-blocks)
    if (sel == 0 && ty == 0) {
        float acc = 0.f;
        for (int cl = 0; cl < 32; ++cl) { float v = tile[cl][tx]; acc += v * v; }
        atomicAdd(&ssq[(size_t)s * LL + r0 + tx], acc);
    }

    // transposed hi/lo bf16 split write (verbatim from old k_split_T)
#pragma unroll
    for (int j = 0; j < 4; ++j) {
        int rl = ty + 8 * j, cl = tx;
        float v = tile[cl][rl];
        __hip_bfloat16 h = __float2bfloat16(v);
        float resid = v - __bfloat162float(h);
        hi[(size_t)(r0 + rl) * CH + c0 + cl] = h;
        lo[(size_t)(r0 + rl) * CH + c0 + cl] = __float2bfloat16(resid);
    }
}

__global__ __launch_bounds__(256) void k_norm_mm(const float* __restrict__ ssq, const float* __restrict__ mk,
                                                 float* __restrict__ invn, float* __restrict__ mmv) {
    int sI = blockIdx.z;
    ssq += (size_t)sI * LL; mk += sI * S_MK; invn += (size_t)sI * LL; mmv += (size_t)sI * LL;
    int p = blockIdx.x * 256 + threadIdx.x;
    int ph = p / GS, pw = p % GS;
    float acc = EPSSUM;
    float msum = 0.f;
    for (int di = -1; di <= 1; ++di)
        for (int dj = -1; dj <= 1; ++dj) {
            int r = ph + di, s = pw + dj;
            if (r >= 0 && r < GS && s >= 0 && s < GS) {
                acc  += ssq[r * GS + s];
                msum += mk[(2 * r) * HW + 2 * s];
            }
        }
    invn[p] = 1.0f / sqrtf(acc);
    mmv[p]  = (msum / 9.0f == 1.0f) ? 1.0f : 0.0f;
}

// W2T[ck][p] = bf16( b[c, 2ph+dy-1, 2pw+dx-1] ), ck = c*16+dy*4+dx
__global__ __launch_bounds__(256) void k_w2T(const float* __restrict__ b, __hip_bfloat16* __restrict__ W2T) {
    int sI = blockIdx.z;
    b += sI * S_IN; W2T += sI * S_W2;
    int ck = blockIdx.y;
    int p  = blockIdx.x * 256 + threadIdx.x;     // gridDim.x = 9
    int c = ck >> 4, dy = (ck >> 2) & 3, dx = ck & 3;
    int ph = p / GS, pw = p % GS;
    int r = 2 * ph + dy - 1, s = 2 * pw + dx - 1;
    float v = 0.f;
    if (r >= 0 && r < HW && s >= 0 && s < HW) v = b[c * HW * HW + r * HW + s];
    W2T[(size_t)ck * LL + p] = __float2bfloat16(v);
}

// ---------------- GEMM1 (split-bf16 MFMA): D = bs fs^T over channels ----------------
__global__ __launch_bounds__(256) void gemm1_mfma(const float* __restrict__ bufB, float* __restrict__ bufA) {
    __shared__ __hip_bfloat16 sAh[128 * 32];
    __shared__ __hip_bfloat16 sAl[128 * 32];
    __shared__ __hip_bfloat16 sBh[128 * 32];
    __shared__ __hip_bfloat16 sBl[128 * 32];
    int sI = blockIdx.z;
    const __hip_bfloat16* base = (const __hip_bfloat16*)(bufB + sI * S_BUF);
    const __hip_bfloat16* Ahi = base;
    const __hip_bfloat16* Alo = Ahi + (size_t)LL * CH;
    const __hip_bfloat16* Bhi = Alo + (size_t)LL * CH;
    const __hip_bfloat16* Blo = Bhi + (size_t)LL * CH;
    float* C = bufA + sI * S_BUF;

    int t = threadIdx.x, lane = t & 63, w = t >> 6;
    int wr = w >> 1, wc = w & 1;
    int m0 = blockIdx.y * 128, n0 = blockIdx.x * 128;

    float4v acc[4][4];
#pragma unroll
    for (int i = 0; i < 4; ++i)
#pragma unroll
        for (int j = 0; j < 4; ++j) acc[i][j] = (float4v){0.f, 0.f, 0.f, 0.f};

    for (int k0 = 0; k0 < 128; k0 += 32) {
#pragma unroll
        for (int it = 0; it < 2; ++it) {
            int chunk = it * 256 + w * 64 + lane;
            int row = chunk >> 2, ps = chunk & 3;
            int pd = ps ^ (row & 3);
            size_t ga = (size_t)(m0 + row) * 128 + k0 + pd * 8;
            size_t gb = (size_t)(n0 + row) * 128 + k0 + pd * 8;
            GLDS16(Ahi + ga, (char*)sAh + (size_t)chunk * 16);
            GLDS16(Alo + ga, (char*)sAl + (size_t)chunk * 16);
            GLDS16(Bhi + gb, (char*)sBh + (size_t)chunk * 16);
            GLDS16(Blo + gb, (char*)sBl + (size_t)chunk * 16);
        }
        __syncthreads();

        int lrow = lane & 15, part = lane >> 4;
        int sw = part ^ (lrow & 3);
        short8 ah[4], al[4], bh[4], bl[4];
#pragma unroll
        for (int i = 0; i < 4; ++i) {
            int slot = (wr * 64 + i * 16 + lrow) * 4 + sw;
            ah[i] = *reinterpret_cast<const short8*>(sAh + (size_t)slot * 8);
            al[i] = *reinterpret_cast<const short8*>(sAl + (size_t)slot * 8);
        }
#pragma unroll
        for (int j = 0; j < 4; ++j) {
            int slot = (wc * 64 + j * 16 + lrow) * 4 + sw;
            bh[j] = *reinterpret_cast<const short8*>(sBh + (size_t)slot * 8);
            bl[j] = *reinterpret_cast<const short8*>(sBl + (size_t)slot * 8);
        }
#pragma unroll
        for (int i = 0; i < 4; ++i)
#pragma unroll
            for (int j = 0; j < 4; ++j) {
                acc[i][j] = __builtin_amdgcn_mfma_f32_16x16x32_bf16(ah[i], bh[j], acc[i][j], 0, 0, 0);
                acc[i][j] = __builtin_amdgcn_mfma_f32_16x16x32_bf16(ah[i], bl[j], acc[i][j], 0, 0, 0);
                acc[i][j] = __builtin_amdgcn_mfma_f32_16x16x32_bf16(al[i], bh[j], acc[i][j], 0, 0, 0);
            }
        __syncthreads();
    }

    int col = lane & 15, rbase = (lane >> 4) * 4;
#pragma unroll
    for (int i = 0; i < 4; ++i)
#pragma unroll
        for (int j = 0; j < 4; ++j)
#pragma unroll
            for (int r = 0; r < 4; ++r) {
                int m = m0 + wr * 64 + i * 16 + rbase + r;
                int n = n0 + wc * 64 + j * 16 + col;
                C[(size_t)m * LL + n] = acc[i][j][r];
            }
}

// ---------------- GEMM2 (bf16 MFMA, bf16 output, TRANSPOSED result) ----------------
// Zt[ck][q] = sum_p W2T[ck][p] * attnT[q][p]. Proven R5 form: plain __syncthreads
// schedule (m97 structure) + XCD-chunked bijective tile swizzle (288 % 8 == 0).
// Closed-out (R5-R10): traffic cut, dbuf, BK=64, counted vmcnt, occupancy cap all
// neutral/regress — the per-K-step stage+drain latency is structural; only the
// 8-phase 256-square template would break it.
__global__ __launch_bounds__(256) void gemm2_mfma(const __hip_bfloat16* __restrict__ W2T_,
                                                  const __hip_bfloat16* __restrict__ attnT_,
                                                  float* __restrict__ bufA) {
    __shared__ __hip_bfloat16 As[128 * 32];
    __shared__ __hip_bfloat16 Bs[128 * 32];
    int sI = blockIdx.z;
    const __hip_bfloat16* A = W2T_ + sI * S_W2;        // [CKN][LL]
    const __hip_bfloat16* B = attnT_ + sI * S_AT;      // [LL][LL]
    __hip_bfloat16* C = (__hip_bfloat16*)(bufA + sI * S_BUF);   // Zt [CKN][LL]

    int t = threadIdx.x;
    int lane = t & 63, w = t >> 6;
    int wr = w >> 1, wc = w & 1;

    // bijective XCD swizzle (nwg = 288 = 8 * 36)
    int flat = blockIdx.y * 18 + blockIdx.x;
    int swz  = (flat & 7) * 36 + (flat >> 3);
    int by = swz / 18, bx = swz % 18;
    int m0 = by * 128, n0 = bx * 128;

    float4v acc[4][4];
#pragma unroll
    for (int i = 0; i < 4; ++i)
#pragma unroll
        for (int j = 0; j < 4; ++j) acc[i][j] = (float4v){0.f, 0.f, 0.f, 0.f};

    for (int k0 = 0; k0 < LL; k0 += 32) {
#pragma unroll
        for (int it = 0; it < 2; ++it) {
            int chunk = it * 256 + w * 64 + lane;
            int row = chunk >> 2, ps = chunk & 3;
            int pd = ps ^ (row & 3);
            const __hip_bfloat16* ga = A + (size_t)(m0 + row) * LL + k0 + pd * 8;
            const __hip_bfloat16* gb = B + (size_t)(n0 + row) * LL + k0 + pd * 8;
            GLDS16(ga, (char*)As + (size_t)chunk * 16);
            GLDS16(gb, (char*)Bs + (size_t)chunk * 16);
        }
        __syncthreads();

        int lrow = lane & 15, part = lane >> 4;
        int sw = part ^ (lrow & 3);
        short8 afrag[4], bfrag[4];
#pragma unroll
        for (int i = 0; i < 4; ++i) {
            int slot = (wr * 64 + i * 16 + lrow) * 4 + sw;
            afrag[i] = *reinterpret_cast<const short8*>(As + (size_t)slot * 8);
        }
#pragma unroll
        for (int j = 0; j < 4; ++j) {
            int slot = (wc * 64 + j * 16 + lrow) * 4 + sw;
            bfrag[j] = *reinterpret_cast<const short8*>(Bs + (size_t)slot * 8);
        }
#pragma unroll
        for (int i = 0; i < 4; ++i)
#pragma unroll
            for (int j = 0; j < 4; ++j)
                acc[i][j] = __builtin_amdgcn_mfma_f32_16x16x32_bf16(afrag[i], bfrag[j], acc[i][j], 0, 0, 0);
        __syncthreads();
    }

    int col = lane & 15, rbase = (lane >> 4) * 4;
#pragma unroll
    for (int i = 0; i < 4; ++i)
#pragma unroll
        for (int j = 0; j < 4; ++j)
#pragma unroll
            for (int r = 0; r < 4; ++r) {
                int m = m0 + wr * 64 + i * 16 + rbase + r;
                int n = n0 + wc * 64 + j * 16 + col;
                C[(size_t)m * LL + n] = __float2bfloat16(acc[i][j][r]);
            }
}

// ---------------- correlation assembly (float4-vectorized, unbatched: max TLP) ----------------
// yi[p][q] = invn[p] * sum_{valid di,dj} D[p+48di+dj][q+48di+dj]
// R3/R9 lesson: this latency-bound stencil lives off massive TLP (27.6k blocks);
// any batching/fusion that cuts block count regresses.
__global__ __launch_bounds__(192) void k_corr_v4(const float* __restrict__ bufA, const float* __restrict__ invn,
                                                 float* __restrict__ bufB) {
    int sI = blockIdx.z;
    const float* D = bufA + sI * S_BUF;
    float* yi = bufB + sI * S_BUF;
    invn += (size_t)sI * LL;

    int p  = blockIdx.y;
    int qi = blockIdx.x * 192 + threadIdx.x;     // 0..575
    int q4 = qi * 4;
    int qh = q4 / GS, qw0 = q4 % GS;
    int ph = p / GS, pw = p % GS;

    float4 acc = {0.f, 0.f, 0.f, 0.f};
#pragma unroll
    for (int di = -1; di <= 1; ++di) {
        int rp = ph + di, tq = qh + di;
        if (rp < 0 || rp >= GS || tq < 0 || tq >= GS) continue;
        int r0 = rp * GS + pw;           // = p + 48*di
        int c0 = tq * GS + qw0;          // = q4 + 48*di (4-aligned)
        // dj = 0
        {
            float4 Cc = ld4(D + (size_t)r0 * LL + c0);
            acc.x += Cc.x; acc.y += Cc.y; acc.z += Cc.z; acc.w += Cc.w;
        }
        // dj = -1 (row r0-1, cols c0-1..c0+2); valid iff pw>0; elem0 masked iff qw0==0
        if (pw > 0) {
            const float* rowm = D + (size_t)(r0 - 1) * LL;
            float4 L  = ld4(rowm + (qw0 > 0 ? c0 - 4 : c0));
            float4 Cm = ld4(rowm + c0);
            acc.x += (qw0 > 0 ? L.w : 0.f);
            acc.y += Cm.x; acc.z += Cm.y; acc.w += Cm.z;
        }
        // dj = +1 (row r0+1, cols c0+1..c0+4); valid iff pw<47; elem3 masked iff qw0==44
        if (pw < GS - 1) {
            const float* rowp = D + (size_t)(r0 + 1) * LL;
            float4 Cp = ld4(rowp + c0);
            float4 R  = ld4(rowp + (qw0 < GS - 4 ? c0 + 4 : c0));
            acc.x += Cp.y; acc.y += Cp.z; acc.z += Cp.w;
            acc.w += (qw0 < GS - 4 ? R.x : 0.f);
        }
    }
    float inv = invn[p];
    float4 outv = {inv * acc.x, inv * acc.y, inv * acc.z, inv * acc.w};
    *reinterpret_cast<float4*>(yi + (size_t)p * LL + q4) = outv;
}

// ---------------- fuse1 (float4-vectorized, unbatched): S1[a][b] = sum_d yi[a+d][b+d] ----------------
__global__ __launch_bounds__(192) void k_fuse1_v4(const float* __restrict__ bufB, float* __restrict__ bufA) {
    int sI = blockIdx.z;
    const float* yi = bufB + sI * S_BUF;
    float* S1 = bufA + sI * S_BUF;
    int a  = blockIdx.y;
    int bi = blockIdx.x * 192 + threadIdx.x;
    int b4 = bi * 4;

    float4 acc = ld4(yi + (size_t)a * LL + b4);          // d = 0
    if (a > 0) {                                          // d = -1: cols b4-1..b4+2
        const float* rowm = yi + (size_t)(a - 1) * LL;
        float4 L  = ld4(rowm + (b4 > 0 ? b4 - 4 : b4));
        float4 Cm = ld4(rowm + b4);
        acc.x += (b4 > 0 ? L.w : 0.f);
        acc.y += Cm.x; acc.z += Cm.y; acc.w += Cm.z;
    }
    if (a < LL - 1) {                                     // d = +1: cols b4+1..b4+4
        const float* rowp = yi + (size_t)(a + 1) * LL;
        float4 Cp = ld4(rowp + b4);
        float4 R  = ld4(rowp + (b4 < LL - 4 ? b4 + 4 : b4));
        acc.x += Cp.y; acc.y += Cp.z; acc.z += Cp.w;
        acc.w += (b4 < LL - 4 ? R.x : 0.f);
    }
    *reinterpret_cast<float4*>(S1 + (size_t)a * LL + b4) = acc;
}

__device__ __forceinline__ int gmap(int x) { int hi = x / GS; int lo = x - hi * GS; return lo * GS + hi; }

// fuse2 + softmax partials, 4-wide: within a 4-aligned q-quad qh is constant, and
// gmap(b0+e) = q + 48e (contiguous, 4-aligned) except at qh+e wrap -> scalar fallback.
__global__ __launch_bounds__(192) void k_fuse2_sm_v4(const float* __restrict__ bufA, const float* __restrict__ mmv,
                                                     float* __restrict__ bufB,
                                                     float* __restrict__ pmax, float* __restrict__ psum) {
    int sI = blockIdx.z;
    const float* S1 = bufA + sI * S_BUF;
    float* S2 = bufB + sI * S_BUF;
    mmv += (size_t)sI * LL; pmax += sI * S_PM; psum += sI * S_PM;
    int qi = blockIdx.x * 192 + threadIdx.x;   // 0..575
    int q4 = qi * 4;
    int qh = q4 / GS, qw0 = q4 % GS;
    int p0 = blockIdx.y * PCH2;
    float mxa[4], sma[4];
#pragma unroll
    for (int j = 0; j < 4; ++j) { mxa[j] = -1e30f; sma[j] = 0.f; }

    for (int i = 0; i < PCH2; ++i) {
        int p = p0 + i;
        int ph = p / GS, pw = p % GS;
        int a0 = pw * GS + ph;
        float sarr[4] = {0.f, 0.f, 0.f, 0.f};
#pragma unroll
        for (int e = -1; e <= 1; ++e) {
            int ae = a0 + e;
            if (ae < 0 || ae >= LL) continue;                 // uniform in block (p uniform)
            int Ar = gmap(ae);
            const float* Rw = S1 + (size_t)Ar * LL;
            int qe = qh + e;
            if (qe >= 0 && qe < GS) {                          // fast path: contiguous quad
                float4 v = ld4(Rw + q4 + 48 * e);
                sarr[0] += v.x; sarr[1] += v.y; sarr[2] += v.z; sarr[3] += v.w;
            } else {                                           // qh wrap: scalar gmap per element
#pragma unroll
                for (int j = 0; j < 4; ++j) {
                    int be = (qw0 + j) * GS + qh + e;
                    if (be >= 0 && be < LL) {
                        int bh = be / GS, bw = be % GS;
                        sarr[j] += Rw[bw * GS + bh];
                    }
                }
            }
        }
        float4 sv = {sarr[0], sarr[1], sarr[2], sarr[3]};
        *reinterpret_cast<float4*>(S2 + (size_t)p * LL + q4) = sv;
        float mv = mmv[p];
#pragma unroll
        for (int j = 0; j < 4; ++j) {
            float lg = (mv != 0.f) ? SCALE * sarr[j] : 0.f;
            float nm = fmaxf(mxa[j], lg);
            sma[j] = sma[j] * __expf(mxa[j] - nm) + __expf(lg - nm);
            mxa[j] = nm;
        }
    }
    float4 mo = {mxa[0], mxa[1], mxa[2], mxa[3]};
    float4 so = {sma[0], sma[1], sma[2], sma[3]};
    *reinterpret_cast<float4*>(pmax + blockIdx.y * LL + q4) = mo;
    *reinterpret_cast<float4*>(psum + blockIdx.y * LL + q4) = so;
}

// final softmax max/denominator: 4-way tree over 72 chunks, 64 q per block
__global__ __launch_bounds__(256) void k_sm2(const float* __restrict__ pmax, const float* __restrict__ psum,
                                             float* __restrict__ Mq, float* __restrict__ Dq) {
    __shared__ float red[4][64];
    int sI = blockIdx.z;
    pmax += sI * S_PM; psum += sI * S_PM; Mq += (size_t)sI * LL; Dq += (size_t)sI * LL;
    int t = threadIdx.x;
    int ql = t & 63, g = t >> 6;
    int q = blockIdx.x * 64 + ql;
    float mx = -1e30f;
    for (int ch = g * 18; ch < g * 18 + 18; ++ch) mx = fmaxf(mx, pmax[(size_t)ch * LL + q]);
    red[g][ql] = mx;
    __syncthreads();
    float mall = fmaxf(fmaxf(red[0][ql], red[1][ql]), fmaxf(red[2][ql], red[3][ql]));
    float sm = 0.f;
    for (int ch = g * 18; ch < g * 18 + 18; ++ch)
        sm += psum[(size_t)ch * LL + q] * __expf(pmax[(size_t)ch * LL + q] - mall);
    __syncthreads();
    red[g][ql] = sm;
    __syncthreads();
    if (g == 0) {
        Mq[q] = mall;
        Dq[q] = (red[0][ql] + red[1][ql]) + (red[2][ql] + red[3][ql]);
    }
}

// attnT[q][p] = bf16( mmv[p] * exp(10*S2[p][q] - Mq[q]) / Dq[q] ) via 32x32 LDS transpose
__global__ __launch_bounds__(256) void k_sm3T(const float* __restrict__ bufB, const float* __restrict__ mmv,
                                              const float* __restrict__ Mq, const float* __restrict__ Dq,
                                              __hip_bfloat16* __restrict__ attnT) {
    __shared__ float tile[32][33];
    int sI = blockIdx.z;
    const float* S2 = bufB + sI * S_BUF;
    mmv += (size_t)sI * LL; Mq += (size_t)sI * LL; Dq += (size_t)sI * LL; attnT += sI * S_AT;
    int tx = threadIdx.x & 31, ty = threadIdx.x >> 5;
    int p0 = blockIdx.y * 32, q0 = blockIdx.x * 32;
    int q = q0 + tx;
    float mq = Mq[q], dq = Dq[q];
#pragma unroll
    for (int j = 0; j < 4; ++j) {
        int p = p0 + ty + 8 * j;
        float v = S2[(size_t)p * LL + q];
        float attn = (mmv[p] != 0.f) ? __expf(SCALE * v - mq) / dq : 0.f;
        tile[ty + 8 * j][tx] = attn;
    }
    __syncthreads();
#pragma unroll
    for (int j = 0; j < 4; ++j) {
        int qq = q0 + ty + 8 * j;
        attnT[(size_t)qq * LL + p0 + tx] = __float2bfloat16(tile[tx][ty + 8 * j]);
    }
}

// ---------------- output assembly (reads bf16 Zt [CKN][LL]) ----------------
__global__ __launch_bounds__(256) void k_out(const float* __restrict__ bufA, float* __restrict__ out) {
    int sI = blockIdx.z;
    const __hip_bfloat16* Z = (const __hip_bfloat16*)(bufA + sI * S_BUF);   // Zt [CKN][LL]
    out += sI * S_IN;
    int c  = blockIdx.y;
    int yx = blockIdx.x * 256 + threadIdx.x;     // gridDim.x = 36
    int y = yx / HW, x = yx % HW;
    int u = y >> 1, a = y & 1, v = x >> 1, w = x & 1;
    int qh1 = u + a - 1, qh2 = u + a, qw1 = v + w - 1, qw2 = v + w;
    int cb = c * 16;
    float s = 0.f;
    if (qh1 >= 0) {
        if (qw1 >= 0)  s += __bfloat162float(Z[(size_t)(cb + (3 - a) * 4 + (3 - w)) * LL + qh1 * GS + qw1]);
        if (qw2 < GS)  s += __bfloat162float(Z[(size_t)(cb + (3 - a) * 4 + (1 - w)) * LL + qh1 * GS + qw2]);
    }
    if (qh2 < GS) {
        if (qw1 >= 0)  s += __bfloat162float(Z[(size_t)(cb + (1 - a) * 4 + (3 - w)) * LL + qh2 * GS + qw1]);
        if (qw2 < GS)  s += __bfloat162float(Z[(size_t)(cb + (1 - a) * 4 + (1 - w)) * LL + qh2 * GS + qw2]);
    }
    out[(size_t)c * HW * HW + yx] = 0.25f * s;
}

// ---------------- launch ----------------

extern "C" void kernel_launch(void* const* d_in, const int* in_sizes, int n_in,
                              void* d_out, int out_size, void* d_ws, size_t ws_size,
                              hipStream_t stream) {
    const float* b_all = (const float*)d_in[0];
    const float* f_all = (const float*)d_in[1];
    const float* m_all = (const float*)d_in[2];
    float* out = (float*)d_out;
    float* ws  = (float*)d_ws;

    const size_t perF = 5 * (size_t)LL + 2 * S_PM + 2 * S_BUF + S_W2 / 2 + S_AT / 2;
    const size_t perB = perF * sizeof(float);
    int nb = (ws_size >= NS * perB) ? NS : ((ws_size >= 2 * perB) ? 2 : 1);

    size_t off = 0;
    float* ssq  = ws + off; off += nb * (size_t)LL;
    float* invn = ws + off; off += nb * (size_t)LL;
    float* mmv  = ws + off; off += nb * (size_t)LL;
    float* Mq   = ws + off; off += nb * (size_t)LL;
    float* Dq   = ws + off; off += nb * (size_t)LL;
    float* pmax = ws + off; off += nb * S_PM;
    float* psum = ws + off; off += nb * S_PM;
    float* bufA = ws + off; off += nb * S_BUF;   // D -> S1 -> Zt(bf16)
    float* bufB = ws + off; off += nb * S_BUF;   // (splits) -> yi -> S2
    __hip_bfloat16* W2T   = (__hip_bfloat16*)(ws + off); off += nb * S_W2 / 2;
    __hip_bfloat16* attnT = (__hip_bfloat16*)(ws + off); off += nb * S_AT / 2;

    for (int s0 = 0; s0 < NS; s0 += nb) {
        const float* b  = b_all + s0 * S_IN;
        const float* f  = f_all + s0 * S_IN;
        const float* mk = m_all + s0 * S_MK;
        float* outp = out + s0 * S_IN;

        hipMemsetAsync(ssq, 0, nb * LL * sizeof(float), stream);
        k_stage_split<<<dim3(72, 4, 2 * nb), 256, 0, stream>>>(b, f, ssq, bufB);
        k_norm_mm    <<<dim3(9, 1, nb), 256, 0, stream>>>(ssq, mk, invn, mmv);
        k_w2T        <<<dim3(9, CKN, nb), 256, 0, stream>>>(b, W2T);

        gemm1_mfma   <<<dim3(18, 18, nb), 256, 0, stream>>>(bufB, bufA);
        k_corr_v4    <<<dim3(3, LL, nb), 192, 0, stream>>>(bufA, invn, bufB);
        k_fuse1_v4   <<<dim3(3, LL, nb), 192, 0, stream>>>(bufB, bufA);
        k_fuse2_sm_v4<<<dim3(3, NCH2, nb), 192, 0, stream>>>(bufA, mmv, bufB, pmax, psum);

        k_sm2      <<<dim3(36, 1, nb), 256, 0, stream>>>(pmax, psum, Mq, Dq);
        k_sm3T     <<<dim3(72, 72, nb), 256, 0, stream>>>(bufB, mmv, Mq, Dq, attnT);

        gemm2_mfma <<<dim3(LL / 128, CKN / 128, nb), 256, 0, stream>>>(W2T, attnT, bufA);
        k_out      <<<dim3(36, CH, nb), 256, 0, stream>>>(bufA, outp);
    }
}

// Round 12
// 519.968 us; speedup vs baseline: 1.0523x; 1.0054x over previous
//
#include <hip/hip_runtime.h>
#include <hip/hip_bf16.h>
#include <math.h>

#define NS   4      // batch
#define CH   128    // channels
#define HW   96     // full-res H=W
#define GS   48     // half-res grid side
#define LL   2304   // GS*GS
#define CKN  2048   // CH*16 (4x4 taps)
#define SCALE 10.0f
#define EPSSUM 0.1152f  // 1152 * 1e-4
#define PCH2 32     // softmax p-chunk
#define NCH2 72     // 2304/32

// per-sample strides (elements)
#define S_IN  ((size_t)CH * HW * HW)   // b / f / out
#define S_MK  ((size_t)HW * HW)        // mask
#define S_PM  ((size_t)NCH2 * LL)      // pmax / psum
#define S_BUF ((size_t)LL * LL)        // bufA / bufB (fp32)
#define S_W2  ((size_t)CKN * LL)       // W2T (bf16 elems)
#define S_AT  ((size_t)LL * LL)        // attnT (bf16 elems)

typedef __attribute__((ext_vector_type(8))) short short8;
typedef __attribute__((ext_vector_type(4))) float float4v;

#define GLDS16(gptr, lptr) \
    __builtin_amdgcn_global_load_lds((const __attribute__((address_space(1))) void*)(gptr), \
        (__attribute__((address_space(3))) void*)(lptr), 16, 0, 0)

__device__ __forceinline__ float4 ld4(const float* p) { return *reinterpret_cast<const float4*>(p); }

// ---------------- fused staging: subsample + ssq partials + transposed hi/lo bf16 split ----------------
// R12: ssq via 4 disjoint per-channel-group partials (plain stores, each slot written
// exactly once) — no memset, no atomics, deterministic invn.
__global__ __launch_bounds__(256) void k_stage_split(const float* __restrict__ b, const float* __restrict__ f,
                                                     float* __restrict__ ssq4, float* __restrict__ bufB) {
    __shared__ float tile[32][33];
    int z = blockIdx.z;
    int s = z >> 1, sel = z & 1;
    const float* X = (sel ? f : b) + s * S_IN;
    __hip_bfloat16* base = (__hip_bfloat16*)(bufB + s * S_BUF);
    __hip_bfloat16* hi = base + (size_t)sel * 2 * LL * CH;
    __hip_bfloat16* lo = hi + (size_t)LL * CH;
    int r0 = blockIdx.x * 32, c0 = blockIdx.y * 32;   // r0 over rs (LL), c0 over CH
    int tx = threadIdx.x & 31, ty = threadIdx.x >> 5;

    // load tile[c_local][rs_local] from subsampled source
#pragma unroll
    for (int j = 0; j < 4; ++j) {
        int c  = c0 + ty + 8 * j;
        int rs = r0 + tx;
        int r = rs / GS, ss_ = rs % GS;
        tile[ty + 8 * j][tx] = X[(size_t)c * HW * HW + (2 * r) * HW + 2 * ss_];
    }
    __syncthreads();

    // ssq partial (b only): thread tx owns rs = r0+tx; sum channels c0..c0+31 in order;
    // plain store to the (c-group, rs) slot — written exactly once across the grid.
    if (sel == 0 && ty == 0) {
        float acc = 0.f;
        for (int cl = 0; cl < 32; ++cl) { float v = tile[cl][tx]; acc += v * v; }
        ssq4[(size_t)s * 4 * LL + (size_t)blockIdx.y * LL + r0 + tx] = acc;
    }

    // transposed hi/lo bf16 split write
#pragma unroll
    for (int j = 0; j < 4; ++j) {
        int rl = ty + 8 * j, cl = tx;
        float v = tile[cl][rl];
        __hip_bfloat16 h = __float2bfloat16(v);
        float resid = v - __bfloat162float(h);
        hi[(size_t)(r0 + rl) * CH + c0 + cl] = h;
        lo[(size_t)(r0 + rl) * CH + c0 + cl] = __float2bfloat16(resid);
    }
}

// ---------------- W2T gather + (merged) norm/mask kernel ----------------
// W2T[ck][p] = bf16( b[c, 2ph+dy-1, 2pw+dx-1] ), ck = c*16+dy*4+dx.
// blockIdx.y == 0 blocks additionally compute invn/mmv (old k_norm_mm).
__global__ __launch_bounds__(256) void k_w2T_norm(const float* __restrict__ b, const float* __restrict__ mk,
                                                  const float* __restrict__ ssq4,
                                                  float* __restrict__ invn, float* __restrict__ mmv,
                                                  __hip_bfloat16* __restrict__ W2T) {
    int sI = blockIdx.z;
    {
        const float* bb = b + sI * S_IN;
        __hip_bfloat16* W = W2T + sI * S_W2;
        int ck = blockIdx.y;
        int p  = blockIdx.x * 256 + threadIdx.x;     // gridDim.x = 9
        int c = ck >> 4, dy = (ck >> 2) & 3, dx = ck & 3;
        int ph = p / GS, pw = p % GS;
        int r = 2 * ph + dy - 1, s = 2 * pw + dx - 1;
        float v = 0.f;
        if (r >= 0 && r < HW && s >= 0 && s < HW) v = bb[c * HW * HW + r * HW + s];
        W[(size_t)ck * LL + p] = __float2bfloat16(v);
    }
    if (blockIdx.y == 0) {
        const float* sq = ssq4 + (size_t)sI * 4 * LL;
        const float* m  = mk + sI * S_MK;
        float* iv = invn + (size_t)sI * LL;
        float* mv = mmv + (size_t)sI * LL;
        int p = blockIdx.x * 256 + threadIdx.x;
        int ph = p / GS, pw = p % GS;
        float acc = EPSSUM;
        float msum = 0.f;
        for (int di = -1; di <= 1; ++di)
            for (int dj = -1; dj <= 1; ++dj) {
                int r = ph + di, s = pw + dj;
                if (r >= 0 && r < GS && s >= 0 && s < GS) {
                    int idx = r * GS + s;
                    acc  += sq[idx] + sq[LL + idx] + sq[2 * LL + idx] + sq[3 * LL + idx];
                    msum += m[(2 * r) * HW + 2 * s];
                }
            }
        iv[p] = 1.0f / sqrtf(acc);
        mv[p] = (msum / 9.0f == 1.0f) ? 1.0f : 0.0f;
    }
}

// ---------------- GEMM1 (split-bf16 MFMA): D = bs fs^T over channels ----------------
__global__ __launch_bounds__(256) void gemm1_mfma(const float* __restrict__ bufB, float* __restrict__ bufA) {
    __shared__ __hip_bfloat16 sAh[128 * 32];
    __shared__ __hip_bfloat16 sAl[128 * 32];
    __shared__ __hip_bfloat16 sBh[128 * 32];
    __shared__ __hip_bfloat16 sBl[128 * 32];
    int sI = blockIdx.z;
    const __hip_bfloat16* base = (const __hip_bfloat16*)(bufB + sI * S_BUF);
    const __hip_bfloat16* Ahi = base;
    const __hip_bfloat16* Alo = Ahi + (size_t)LL * CH;
    const __hip_bfloat16* Bhi = Alo + (size_t)LL * CH;
    const __hip_bfloat16* Blo = Bhi + (size_t)LL * CH;
    float* C = bufA + sI * S_BUF;

    int t = threadIdx.x, lane = t & 63, w = t >> 6;
    int wr = w >> 1, wc = w & 1;
    int m0 = blockIdx.y * 128, n0 = blockIdx.x * 128;

    float4v acc[4][4];
#pragma unroll
    for (int i = 0; i < 4; ++i)
#pragma unroll
        for (int j = 0; j < 4; ++j) acc[i][j] = (float4v){0.f, 0.f, 0.f, 0.f};

    for (int k0 = 0; k0 < 128; k0 += 32) {
#pragma unroll
        for (int it = 0; it < 2; ++it) {
            int chunk = it * 256 + w * 64 + lane;
            int row = chunk >> 2, ps = chunk & 3;
            int pd = ps ^ (row & 3);
            size_t ga = (size_t)(m0 + row) * 128 + k0 + pd * 8;
            size_t gb = (size_t)(n0 + row) * 128 + k0 + pd * 8;
            GLDS16(Ahi + ga, (char*)sAh + (size_t)chunk * 16);
            GLDS16(Alo + ga, (char*)sAl + (size_t)chunk * 16);
            GLDS16(Bhi + gb, (char*)sBh + (size_t)chunk * 16);
            GLDS16(Blo + gb, (char*)sBl + (size_t)chunk * 16);
        }
        __syncthreads();

        int lrow = lane & 15, part = lane >> 4;
        int sw = part ^ (lrow & 3);
        short8 ah[4], al[4], bh[4], bl[4];
#pragma unroll
        for (int i = 0; i < 4; ++i) {
            int slot = (wr * 64 + i * 16 + lrow) * 4 + sw;
            ah[i] = *reinterpret_cast<const short8*>(sAh + (size_t)slot * 8);
            al[i] = *reinterpret_cast<const short8*>(sAl + (size_t)slot * 8);
        }
#pragma unroll
        for (int j = 0; j < 4; ++j) {
            int slot = (wc * 64 + j * 16 + lrow) * 4 + sw;
            bh[j] = *reinterpret_cast<const short8*>(sBh + (size_t)slot * 8);
            bl[j] = *reinterpret_cast<const short8*>(sBl + (size_t)slot * 8);
        }
#pragma unroll
        for (int i = 0; i < 4; ++i)
#pragma unroll
            for (int j = 0; j < 4; ++j) {
                acc[i][j] = __builtin_amdgcn_mfma_f32_16x16x32_bf16(ah[i], bh[j], acc[i][j], 0, 0, 0);
                acc[i][j] = __builtin_amdgcn_mfma_f32_16x16x32_bf16(ah[i], bl[j], acc[i][j], 0, 0, 0);
                acc[i][j] = __builtin_amdgcn_mfma_f32_16x16x32_bf16(al[i], bh[j], acc[i][j], 0, 0, 0);
            }
        __syncthreads();
    }

    int col = lane & 15, rbase = (lane >> 4) * 4;
#pragma unroll
    for (int i = 0; i < 4; ++i)
#pragma unroll
        for (int j = 0; j < 4; ++j)
#pragma unroll
            for (int r = 0; r < 4; ++r) {
                int m = m0 + wr * 64 + i * 16 + rbase + r;
                int n = n0 + wc * 64 + j * 16 + col;
                C[(size_t)m * LL + n] = acc[i][j][r];
            }
}

// ---------------- GEMM2 (bf16 MFMA, bf16 output, TRANSPOSED result) ----------------
// Zt[ck][q] = sum_p W2T[ck][p] * attnT[q][p]. Proven R5 form: plain __syncthreads
// schedule (m97 structure) + XCD-chunked bijective tile swizzle (288 % 8 == 0).
// Closed-out (R5-R10): traffic cut, dbuf, BK=64, counted vmcnt, occupancy cap all
// neutral/regress — the per-K-step stage+drain latency is structural.
__global__ __launch_bounds__(256) void gemm2_mfma(const __hip_bfloat16* __restrict__ W2T_,
                                                  const __hip_bfloat16* __restrict__ attnT_,
                                                  float* __restrict__ bufA) {
    __shared__ __hip_bfloat16 As[128 * 32];
    __shared__ __hip_bfloat16 Bs[128 * 32];
    int sI = blockIdx.z;
    const __hip_bfloat16* A = W2T_ + sI * S_W2;        // [CKN][LL]
    const __hip_bfloat16* B = attnT_ + sI * S_AT;      // [LL][LL]
    __hip_bfloat16* C = (__hip_bfloat16*)(bufA + sI * S_BUF);   // Zt [CKN][LL]

    int t = threadIdx.x;
    int lane = t & 63, w = t >> 6;
    int wr = w >> 1, wc = w & 1;

    // bijective XCD swizzle (nwg = 288 = 8 * 36)
    int flat = blockIdx.y * 18 + blockIdx.x;
    int swz  = (flat & 7) * 36 + (flat >> 3);
    int by = swz / 18, bx = swz % 18;
    int m0 = by * 128, n0 = bx * 128;

    float4v acc[4][4];
#pragma unroll
    for (int i = 0; i < 4; ++i)
#pragma unroll
        for (int j = 0; j < 4; ++j) acc[i][j] = (float4v){0.f, 0.f, 0.f, 0.f};

    for (int k0 = 0; k0 < LL; k0 += 32) {
#pragma unroll
        for (int it = 0; it < 2; ++it) {
            int chunk = it * 256 + w * 64 + lane;
            int row = chunk >> 2, ps = chunk & 3;
            int pd = ps ^ (row & 3);
            const __hip_bfloat16* ga = A + (size_t)(m0 + row) * LL + k0 + pd * 8;
            const __hip_bfloat16* gb = B + (size_t)(n0 + row) * LL + k0 + pd * 8;
            GLDS16(ga, (char*)As + (size_t)chunk * 16);
            GLDS16(gb, (char*)Bs + (size_t)chunk * 16);
        }
        __syncthreads();

        int lrow = lane & 15, part = lane >> 4;
        int sw = part ^ (lrow & 3);
        short8 afrag[4], bfrag[4];
#pragma unroll
        for (int i = 0; i < 4; ++i) {
            int slot = (wr * 64 + i * 16 + lrow) * 4 + sw;
            afrag[i] = *reinterpret_cast<const short8*>(As + (size_t)slot * 8);
        }
#pragma unroll
        for (int j = 0; j < 4; ++j) {
            int slot = (wc * 64 + j * 16 + lrow) * 4 + sw;
            bfrag[j] = *reinterpret_cast<const short8*>(Bs + (size_t)slot * 8);
        }
#pragma unroll
        for (int i = 0; i < 4; ++i)
#pragma unroll
            for (int j = 0; j < 4; ++j)
                acc[i][j] = __builtin_amdgcn_mfma_f32_16x16x32_bf16(afrag[i], bfrag[j], acc[i][j], 0, 0, 0);
        __syncthreads();
    }

    int col = lane & 15, rbase = (lane >> 4) * 4;
#pragma unroll
    for (int i = 0; i < 4; ++i)
#pragma unroll
        for (int j = 0; j < 4; ++j)
#pragma unroll
            for (int r = 0; r < 4; ++r) {
                int m = m0 + wr * 64 + i * 16 + rbase + r;
                int n = n0 + wc * 64 + j * 16 + col;
                C[(size_t)m * LL + n] = __float2bfloat16(acc[i][j][r]);
            }
}

// ---------------- correlation assembly (float4-vectorized, unbatched: max TLP) ----------------
// yi[p][q] = invn[p] * sum_{valid di,dj} D[p+48di+dj][q+48di+dj]
// R3/R9 lesson: this latency-bound stencil lives off massive TLP (27.6k blocks).
__global__ __launch_bounds__(192) void k_corr_v4(const float* __restrict__ bufA, const float* __restrict__ invn,
                                                 float* __restrict__ bufB) {
    int sI = blockIdx.z;
    const float* D = bufA + sI * S_BUF;
    float* yi = bufB + sI * S_BUF;
    invn += (size_t)sI * LL;

    int p  = blockIdx.y;
    int qi = blockIdx.x * 192 + threadIdx.x;     // 0..575
    int q4 = qi * 4;
    int qh = q4 / GS, qw0 = q4 % GS;
    int ph = p / GS, pw = p % GS;

    float4 acc = {0.f, 0.f, 0.f, 0.f};
#pragma unroll
    for (int di = -1; di <= 1; ++di) {
        int rp = ph + di, tq = qh + di;
        if (rp < 0 || rp >= GS || tq < 0 || tq >= GS) continue;
        int r0 = rp * GS + pw;           // = p + 48*di
        int c0 = tq * GS + qw0;          // = q4 + 48*di (4-aligned)
        // dj = 0
        {
            float4 Cc = ld4(D + (size_t)r0 * LL + c0);
            acc.x += Cc.x; acc.y += Cc.y; acc.z += Cc.z; acc.w += Cc.w;
        }
        // dj = -1 (row r0-1, cols c0-1..c0+2); valid iff pw>0; elem0 masked iff qw0==0
        if (pw > 0) {
            const float* rowm = D + (size_t)(r0 - 1) * LL;
            float4 L  = ld4(rowm + (qw0 > 0 ? c0 - 4 : c0));
            float4 Cm = ld4(rowm + c0);
            acc.x += (qw0 > 0 ? L.w : 0.f);
            acc.y += Cm.x; acc.z += Cm.y; acc.w += Cm.z;
        }
        // dj = +1 (row r0+1, cols c0+1..c0+4); valid iff pw<47; elem3 masked iff qw0==44
        if (pw < GS - 1) {
            const float* rowp = D + (size_t)(r0 + 1) * LL;
            float4 Cp = ld4(rowp + c0);
            float4 R  = ld4(rowp + (qw0 < GS - 4 ? c0 + 4 : c0));
            acc.x += Cp.y; acc.y += Cp.z; acc.z += Cp.w;
            acc.w += (qw0 < GS - 4 ? R.x : 0.f);
        }
    }
    float inv = invn[p];
    float4 outv = {inv * acc.x, inv * acc.y, inv * acc.z, inv * acc.w};
    *reinterpret_cast<float4*>(yi + (size_t)p * LL + q4) = outv;
}

// ---------------- fuse1 (float4-vectorized, unbatched): S1[a][b] = sum_d yi[a+d][b+d] ----------------
__global__ __launch_bounds__(192) void k_fuse1_v4(const float* __restrict__ bufB, float* __restrict__ bufA) {
    int sI = blockIdx.z;
    const float* yi = bufB + sI * S_BUF;
    float* S1 = bufA + sI * S_BUF;
    int a  = blockIdx.y;
    int bi = blockIdx.x * 192 + threadIdx.x;
    int b4 = bi * 4;

    float4 acc = ld4(yi + (size_t)a * LL + b4);          // d = 0
    if (a > 0) {                                          // d = -1: cols b4-1..b4+2
        const float* rowm = yi + (size_t)(a - 1) * LL;
        float4 L  = ld4(rowm + (b4 > 0 ? b4 - 4 : b4));
        float4 Cm = ld4(rowm + b4);
        acc.x += (b4 > 0 ? L.w : 0.f);
        acc.y += Cm.x; acc.z += Cm.y; acc.w += Cm.z;
    }
    if (a < LL - 1) {                                     // d = +1: cols b4+1..b4+4
        const float* rowp = yi + (size_t)(a + 1) * LL;
        float4 Cp = ld4(rowp + b4);
        float4 R  = ld4(rowp + (b4 < LL - 4 ? b4 + 4 : b4));
        acc.x += Cp.y; acc.y += Cp.z; acc.z += Cp.w;
        acc.w += (b4 < LL - 4 ? R.x : 0.f);
    }
    *reinterpret_cast<float4*>(S1 + (size_t)a * LL + b4) = acc;
}

__device__ __forceinline__ int gmap(int x) { int hi = x / GS; int lo = x - hi * GS; return lo * GS + hi; }

// fuse2 + softmax partials, 4-wide: within a 4-aligned q-quad qh is constant, and
// gmap(b0+e) = q + 48e (contiguous, 4-aligned) except at qh+e wrap -> scalar fallback.
__global__ __launch_bounds__(192) void k_fuse2_sm_v4(const float* __restrict__ bufA, const float* __restrict__ mmv,
                                                     float* __restrict__ bufB,
                                                     float* __restrict__ pmax, float* __restrict__ psum) {
    int sI = blockIdx.z;
    const float* S1 = bufA + sI * S_BUF;
    float* S2 = bufB + sI * S_BUF;
    mmv += (size_t)sI * LL; pmax += sI * S_PM; psum += sI * S_PM;
    int qi = blockIdx.x * 192 + threadIdx.x;   // 0..575
    int q4 = qi * 4;
    int qh = q4 / GS, qw0 = q4 % GS;
    int p0 = blockIdx.y * PCH2;
    float mxa[4], sma[4];
#pragma unroll
    for (int j = 0; j < 4; ++j) { mxa[j] = -1e30f; sma[j] = 0.f; }

    for (int i = 0; i < PCH2; ++i) {
        int p = p0 + i;
        int ph = p / GS, pw = p % GS;
        int a0 = pw * GS + ph;
        float sarr[4] = {0.f, 0.f, 0.f, 0.f};
#pragma unroll
        for (int e = -1; e <= 1; ++e) {
            int ae = a0 + e;
            if (ae < 0 || ae >= LL) continue;                 // uniform in block (p uniform)
            int Ar = gmap(ae);
            const float* Rw = S1 + (size_t)Ar * LL;
            int qe = qh + e;
            if (qe >= 0 && qe < GS) {                          // fast path: contiguous quad
                float4 v = ld4(Rw + q4 + 48 * e);
                sarr[0] += v.x; sarr[1] += v.y; sarr[2] += v.z; sarr[3] += v.w;
            } else {                                           // qh wrap: scalar gmap per element
#pragma unroll
                for (int j = 0; j < 4; ++j) {
                    int be = (qw0 + j) * GS + qh + e;
                    if (be >= 0 && be < LL) {
                        int bh = be / GS, bw = be % GS;
                        sarr[j] += Rw[bw * GS + bh];
                    }
                }
            }
        }
        float4 sv = {sarr[0], sarr[1], sarr[2], sarr[3]};
        *reinterpret_cast<float4*>(S2 + (size_t)p * LL + q4) = sv;
        float mv = mmv[p];
#pragma unroll
        for (int j = 0; j < 4; ++j) {
            float lg = (mv != 0.f) ? SCALE * sarr[j] : 0.f;
            float nm = fmaxf(mxa[j], lg);
            sma[j] = sma[j] * __expf(mxa[j] - nm) + __expf(lg - nm);
            mxa[j] = nm;
        }
    }
    float4 mo = {mxa[0], mxa[1], mxa[2], mxa[3]};
    float4 so = {sma[0], sma[1], sma[2], sma[3]};
    *reinterpret_cast<float4*>(pmax + blockIdx.y * LL + q4) = mo;
    *reinterpret_cast<float4*>(psum + blockIdx.y * LL + q4) = so;
}

// ---------------- sm3T + merged final softmax reduction (old k_sm2 folded in) ----------------
// Each block recomputes Mq/Dq for its 32 q's from pmax/psum (8 groups x 9 chunks,
// LDS tree). pmax/psum are L2-resident (663KB/sample); x72 y-block redundancy is cheap.
// Mq bit-identical (max assoc.); Dq fp32 reassociation only (~1e-7 rel).
__global__ __launch_bounds__(256) void k_sm3T_full(const float* __restrict__ bufB, const float* __restrict__ mmv,
                                                   const float* __restrict__ pmax, const float* __restrict__ psum,
                                                   __hip_bfloat16* __restrict__ attnT) {
    __shared__ float tile[32][33];
    __shared__ float redM[8][32];
    __shared__ float redS[8][32];
    int sI = blockIdx.z;
    const float* S2 = bufB + sI * S_BUF;
    mmv += (size_t)sI * LL; pmax += sI * S_PM; psum += sI * S_PM; attnT += sI * S_AT;
    int t = threadIdx.x;
    int tx = t & 31, ty = t >> 5;        // ty doubles as reduction group
    int p0 = blockIdx.y * 32, q0 = blockIdx.x * 32;
    int q = q0 + tx;

    // Mq/Dq for this thread's q: group ty covers chunks [ty*9, ty*9+9)
    float mx = -1e30f;
    for (int ch = ty * 9; ch < ty * 9 + 9; ++ch)
        mx = fmaxf(mx, pmax[(size_t)ch * LL + q]);
    redM[ty][tx] = mx;
    __syncthreads();
    float mall = redM[0][tx];
#pragma unroll
    for (int g = 1; g < 8; ++g) mall = fmaxf(mall, redM[g][tx]);
    float sm = 0.f;
    for (int ch = ty * 9; ch < ty * 9 + 9; ++ch)
        sm += psum[(size_t)ch * LL + q] * __expf(pmax[(size_t)ch * LL + q] - mall);
    redS[ty][tx] = sm;
    __syncthreads();
    float dall = redS[0][tx];
#pragma unroll
    for (int g = 1; g < 8; ++g) dall += redS[g][tx];

    // original sm3T body (32x32 LDS transpose), mq/dq per-lane q = q0 + (t&31)
    float mq = mall, dq = dall;
#pragma unroll
    for (int j = 0; j < 4; ++j) {
        int p = p0 + ty + 8 * j;
        float v = S2[(size_t)p * LL + q];
        float attn = (mmv[p] != 0.f) ? __expf(SCALE * v - mq) / dq : 0.f;
        tile[ty + 8 * j][tx] = attn;
    }
    __syncthreads();
#pragma unroll
    for (int j = 0; j < 4; ++j) {
        int qq = q0 + ty + 8 * j;
        attnT[(size_t)qq * LL + p0 + tx] = __float2bfloat16(tile[tx][ty + 8 * j]);
    }
}

// ---------------- output assembly (reads bf16 Zt [CKN][LL]) ----------------
__global__ __launch_bounds__(256) void k_out(const float* __restrict__ bufA, float* __restrict__ out) {
    int sI = blockIdx.z;
    const __hip_bfloat16* Z = (const __hip_bfloat16*)(bufA + sI * S_BUF);   // Zt [CKN][LL]
    out += sI * S_IN;
    int c  = blockIdx.y;
    int yx = blockIdx.x * 256 + threadIdx.x;     // gridDim.x = 36
    int y = yx / HW, x = yx % HW;
    int u = y >> 1, a = y & 1, v = x >> 1, w = x & 1;
    int qh1 = u + a - 1, qh2 = u + a, qw1 = v + w - 1, qw2 = v + w;
    int cb = c * 16;
    float s = 0.f;
    if (qh1 >= 0) {
        if (qw1 >= 0)  s += __bfloat162float(Z[(size_t)(cb + (3 - a) * 4 + (3 - w)) * LL + qh1 * GS + qw1]);
        if (qw2 < GS)  s += __bfloat162float(Z[(size_t)(cb + (3 - a) * 4 + (1 - w)) * LL + qh1 * GS + qw2]);
    }
    if (qh2 < GS) {
        if (qw1 >= 0)  s += __bfloat162float(Z[(size_t)(cb + (1 - a) * 4 + (3 - w)) * LL + qh2 * GS + qw1]);
        if (qw2 < GS)  s += __bfloat162float(Z[(size_t)(cb + (1 - a) * 4 + (1 - w)) * LL + qh2 * GS + qw2]);
    }
    out[(size_t)c * HW * HW + yx] = 0.25f * s;
}

// ---------------- launch (9 dispatches; no memset) ----------------

extern "C" void kernel_launch(void* const* d_in, const int* in_sizes, int n_in,
                              void* d_out, int out_size, void* d_ws, size_t ws_size,
                              hipStream_t stream) {
    const float* b_all = (const float*)d_in[0];
    const float* f_all = (const float*)d_in[1];
    const float* m_all = (const float*)d_in[2];
    float* out = (float*)d_out;
    float* ws  = (float*)d_ws;

    const size_t perF = 6 * (size_t)LL + 2 * S_PM + 2 * S_BUF + S_W2 / 2 + S_AT / 2;
    const size_t perB = perF * sizeof(float);
    int nb = (ws_size >= NS * perB) ? NS : ((ws_size >= 2 * perB) ? 2 : 1);

    size_t off = 0;
    float* ssq4 = ws + off; off += nb * 4 * (size_t)LL;
    float* invn = ws + off; off += nb * (size_t)LL;
    float* mmv  = ws + off; off += nb * (size_t)LL;
    float* pmax = ws + off; off += nb * S_PM;
    float* psum = ws + off; off += nb * S_PM;
    float* bufA = ws + off; off += nb * S_BUF;   // D -> S1 -> Zt(bf16)
    float* bufB = ws + off; off += nb * S_BUF;   // (splits) -> yi -> S2
    __hip_bfloat16* W2T   = (__hip_bfloat16*)(ws + off); off += nb * S_W2 / 2;
    __hip_bfloat16* attnT = (__hip_bfloat16*)(ws + off); off += nb * S_AT / 2;

    for (int s0 = 0; s0 < NS; s0 += nb) {
        const float* b  = b_all + s0 * S_IN;
        const float* f  = f_all + s0 * S_IN;
        const float* mk = m_all + s0 * S_MK;
        float* outp = out + s0 * S_IN;

        k_stage_split<<<dim3(72, 4, 2 * nb), 256, 0, stream>>>(b, f, ssq4, bufB);
        k_w2T_norm   <<<dim3(9, CKN, nb), 256, 0, stream>>>(b, mk, ssq4, invn, mmv, W2T);

        gemm1_mfma   <<<dim3(18, 18, nb), 256, 0, stream>>>(bufB, bufA);
        k_corr_v4    <<<dim3(3, LL, nb), 192, 0, stream>>>(bufA, invn, bufB);
        k_fuse1_v4   <<<dim3(3, LL, nb), 192, 0, stream>>>(bufB, bufA);
        k_fuse2_sm_v4<<<dim3(3, NCH2, nb), 192, 0, stream>>>(bufA, mmv, bufB, pmax, psum);

        k_sm3T_full  <<<dim3(72, 72, nb), 256, 0, stream>>>(bufB, mmv, pmax, psum, attnT);

        gemm2_mfma   <<<dim3(LL / 128, CKN / 128, nb), 256, 0, stream>>>(W2T, attnT, bufA);
        k_out        <<<dim3(36, CH, nb), 256, 0, stream>>>(bufA, outp);
    }
}

// Round 13
// 485.818 us; speedup vs baseline: 1.1263x; 1.0703x over previous
//
#include <hip/hip_runtime.h>
#include <hip/hip_bf16.h>
#include <math.h>

#define NS   4      // batch
#define CH   128    // channels
#define HW   96     // full-res H=W
#define GS   48     // half-res grid side
#define LL   2304   // GS*GS
#define CKN  2048   // CH*16 (4x4 taps)
#define SCALE 10.0f
#define EPSSUM 0.1152f  // 1152 * 1e-4
#define PCH2 32     // softmax p-chunk
#define NCH2 72     // 2304/32

// per-sample strides (elements)
#define S_IN  ((size_t)CH * HW * HW)   // b / f / out
#define S_MK  ((size_t)HW * HW)        // mask
#define S_PM  ((size_t)NCH2 * LL)      // pmax / psum
#define S_BUF ((size_t)LL * LL)        // bufA / bufB (fp32)
#define S_W2  ((size_t)CKN * LL)       // W2T (bf16 elems)
#define S_AT  ((size_t)LL * LL)        // attnT (bf16 elems)

typedef __attribute__((ext_vector_type(8))) short short8;
typedef __attribute__((ext_vector_type(4))) float float4v;

#define GLDS16(gptr, lptr) \
    __builtin_amdgcn_global_load_lds((const __attribute__((address_space(1))) void*)(gptr), \
        (__attribute__((address_space(3))) void*)(lptr), 16, 0, 0)

__device__ __forceinline__ float4 ld4(const float* p) { return *reinterpret_cast<const float4*>(p); }

// ---------------- fused staging: subsample + ssq partials + transposed hi/lo bf16 split ----------------
__global__ __launch_bounds__(256) void k_stage_split(const float* __restrict__ b, const float* __restrict__ f,
                                                     float* __restrict__ ssq4, float* __restrict__ bufB) {
    __shared__ float tile[32][33];
    int z = blockIdx.z;
    int s = z >> 1, sel = z & 1;
    const float* X = (sel ? f : b) + s * S_IN;
    __hip_bfloat16* base = (__hip_bfloat16*)(bufB + s * S_BUF);
    __hip_bfloat16* hi = base + (size_t)sel * 2 * LL * CH;
    __hip_bfloat16* lo = hi + (size_t)LL * CH;
    int r0 = blockIdx.x * 32, c0 = blockIdx.y * 32;   // r0 over rs (LL), c0 over CH
    int tx = threadIdx.x & 31, ty = threadIdx.x >> 5;

#pragma unroll
    for (int j = 0; j < 4; ++j) {
        int c  = c0 + ty + 8 * j;
        int rs = r0 + tx;
        int r = rs / GS, ss_ = rs % GS;
        tile[ty + 8 * j][tx] = X[(size_t)c * HW * HW + (2 * r) * HW + 2 * ss_];
    }
    __syncthreads();

    if (sel == 0 && ty == 0) {
        float acc = 0.f;
        for (int cl = 0; cl < 32; ++cl) { float v = tile[cl][tx]; acc += v * v; }
        ssq4[(size_t)s * 4 * LL + (size_t)blockIdx.y * LL + r0 + tx] = acc;
    }

#pragma unroll
    for (int j = 0; j < 4; ++j) {
        int rl = ty + 8 * j, cl = tx;
        float v = tile[cl][rl];
        __hip_bfloat16 h = __float2bfloat16(v);
        float resid = v - __bfloat162float(h);
        hi[(size_t)(r0 + rl) * CH + c0 + cl] = h;
        lo[(size_t)(r0 + rl) * CH + c0 + cl] = __float2bfloat16(resid);
    }
}

// ---------------- W2T gather + (merged) norm/mask kernel ----------------
__global__ __launch_bounds__(256) void k_w2T_norm(const float* __restrict__ b, const float* __restrict__ mk,
                                                  const float* __restrict__ ssq4,
                                                  float* __restrict__ invn, float* __restrict__ mmv,
                                                  __hip_bfloat16* __restrict__ W2T) {
    int sI = blockIdx.z;
    {
        const float* bb = b + sI * S_IN;
        __hip_bfloat16* W = W2T + sI * S_W2;
        int ck = blockIdx.y;
        int p  = blockIdx.x * 256 + threadIdx.x;     // gridDim.x = 9
        int c = ck >> 4, dy = (ck >> 2) & 3, dx = ck & 3;
        int ph = p / GS, pw = p % GS;
        int r = 2 * ph + dy - 1, s = 2 * pw + dx - 1;
        float v = 0.f;
        if (r >= 0 && r < HW && s >= 0 && s < HW) v = bb[c * HW * HW + r * HW + s];
        W[(size_t)ck * LL + p] = __float2bfloat16(v);
    }
    if (blockIdx.y == 0) {
        const float* sq = ssq4 + (size_t)sI * 4 * LL;
        const float* m  = mk + sI * S_MK;
        float* iv = invn + (size_t)sI * LL;
        float* mv = mmv + (size_t)sI * LL;
        int p = blockIdx.x * 256 + threadIdx.x;
        int ph = p / GS, pw = p % GS;
        float acc = EPSSUM;
        float msum = 0.f;
        for (int di = -1; di <= 1; ++di)
            for (int dj = -1; dj <= 1; ++dj) {
                int r = ph + di, s = pw + dj;
                if (r >= 0 && r < GS && s >= 0 && s < GS) {
                    int idx = r * GS + s;
                    acc  += sq[idx] + sq[LL + idx] + sq[2 * LL + idx] + sq[3 * LL + idx];
                    msum += m[(2 * r) * HW + 2 * s];
                }
            }
        iv[p] = 1.0f / sqrtf(acc);
        mv[p] = (msum / 9.0f == 1.0f) ? 1.0f : 0.0f;
    }
}

// ---------------- GEMM1 (split-bf16 MFMA): D = bs fs^T over channels ----------------
__global__ __launch_bounds__(256) void gemm1_mfma(const float* __restrict__ bufB, float* __restrict__ bufA) {
    __shared__ __hip_bfloat16 sAh[128 * 32];
    __shared__ __hip_bfloat16 sAl[128 * 32];
    __shared__ __hip_bfloat16 sBh[128 * 32];
    __shared__ __hip_bfloat16 sBl[128 * 32];
    int sI = blockIdx.z;
    const __hip_bfloat16* base = (const __hip_bfloat16*)(bufB + sI * S_BUF);
    const __hip_bfloat16* Ahi = base;
    const __hip_bfloat16* Alo = Ahi + (size_t)LL * CH;
    const __hip_bfloat16* Bhi = Alo + (size_t)LL * CH;
    const __hip_bfloat16* Blo = Bhi + (size_t)LL * CH;
    float* C = bufA + sI * S_BUF;

    int t = threadIdx.x, lane = t & 63, w = t >> 6;
    int wr = w >> 1, wc = w & 1;
    int m0 = blockIdx.y * 128, n0 = blockIdx.x * 128;

    float4v acc[4][4];
#pragma unroll
    for (int i = 0; i < 4; ++i)
#pragma unroll
        for (int j = 0; j < 4; ++j) acc[i][j] = (float4v){0.f, 0.f, 0.f, 0.f};

    for (int k0 = 0; k0 < 128; k0 += 32) {
#pragma unroll
        for (int it = 0; it < 2; ++it) {
            int chunk = it * 256 + w * 64 + lane;
            int row = chunk >> 2, ps = chunk & 3;
            int pd = ps ^ (row & 3);
            size_t ga = (size_t)(m0 + row) * 128 + k0 + pd * 8;
            size_t gb = (size_t)(n0 + row) * 128 + k0 + pd * 8;
            GLDS16(Ahi + ga, (char*)sAh + (size_t)chunk * 16);
            GLDS16(Alo + ga, (char*)sAl + (size_t)chunk * 16);
            GLDS16(Bhi + gb, (char*)sBh + (size_t)chunk * 16);
            GLDS16(Blo + gb, (char*)sBl + (size_t)chunk * 16);
        }
        __syncthreads();

        int lrow = lane & 15, part = lane >> 4;
        int sw = part ^ (lrow & 3);
        short8 ah[4], al[4], bh[4], bl[4];
#pragma unroll
        for (int i = 0; i < 4; ++i) {
            int slot = (wr * 64 + i * 16 + lrow) * 4 + sw;
            ah[i] = *reinterpret_cast<const short8*>(sAh + (size_t)slot * 8);
            al[i] = *reinterpret_cast<const short8*>(sAl + (size_t)slot * 8);
        }
#pragma unroll
        for (int j = 0; j < 4; ++j) {
            int slot = (wc * 64 + j * 16 + lrow) * 4 + sw;
            bh[j] = *reinterpret_cast<const short8*>(sBh + (size_t)slot * 8);
            bl[j] = *reinterpret_cast<const short8*>(sBl + (size_t)slot * 8);
        }
#pragma unroll
        for (int i = 0; i < 4; ++i)
#pragma unroll
            for (int j = 0; j < 4; ++j) {
                acc[i][j] = __builtin_amdgcn_mfma_f32_16x16x32_bf16(ah[i], bh[j], acc[i][j], 0, 0, 0);
                acc[i][j] = __builtin_amdgcn_mfma_f32_16x16x32_bf16(ah[i], bl[j], acc[i][j], 0, 0, 0);
                acc[i][j] = __builtin_amdgcn_mfma_f32_16x16x32_bf16(al[i], bh[j], acc[i][j], 0, 0, 0);
            }
        __syncthreads();
    }

    int col = lane & 15, rbase = (lane >> 4) * 4;
#pragma unroll
    for (int i = 0; i < 4; ++i)
#pragma unroll
        for (int j = 0; j < 4; ++j)
#pragma unroll
            for (int r = 0; r < 4; ++r) {
                int m = m0 + wr * 64 + i * 16 + rbase + r;
                int n = n0 + wc * 64 + j * 16 + col;
                C[(size_t)m * LL + n] = acc[i][j][r];
            }
}

// ---------------- GEMM2 (bf16 MFMA, bf16 output, TRANSPOSED result) ----------------
// Proven R5 form. R5-R10 falsification set: traffic cut, dbuf, BK=64, counted vmcnt,
// occupancy all neutral/regress. Next step would be the 8-phase 256-sq template, which
// requires race-screening unavailable headlessly — closed for this session.
__global__ __launch_bounds__(256) void gemm2_mfma(const __hip_bfloat16* __restrict__ W2T_,
                                                  const __hip_bfloat16* __restrict__ attnT_,
                                                  float* __restrict__ bufA) {
    __shared__ __hip_bfloat16 As[128 * 32];
    __shared__ __hip_bfloat16 Bs[128 * 32];
    int sI = blockIdx.z;
    const __hip_bfloat16* A = W2T_ + sI * S_W2;        // [CKN][LL]
    const __hip_bfloat16* B = attnT_ + sI * S_AT;      // [LL][LL]
    __hip_bfloat16* C = (__hip_bfloat16*)(bufA + sI * S_BUF);   // Zt [CKN][LL]

    int t = threadIdx.x;
    int lane = t & 63, w = t >> 6;
    int wr = w >> 1, wc = w & 1;

    // bijective XCD swizzle (nwg = 288 = 8 * 36)
    int flat = blockIdx.y * 18 + blockIdx.x;
    int swz  = (flat & 7) * 36 + (flat >> 3);
    int by = swz / 18, bx = swz % 18;
    int m0 = by * 128, n0 = bx * 128;

    float4v acc[4][4];
#pragma unroll
    for (int i = 0; i < 4; ++i)
#pragma unroll
        for (int j = 0; j < 4; ++j) acc[i][j] = (float4v){0.f, 0.f, 0.f, 0.f};

    for (int k0 = 0; k0 < LL; k0 += 32) {
#pragma unroll
        for (int it = 0; it < 2; ++it) {
            int chunk = it * 256 + w * 64 + lane;
            int row = chunk >> 2, ps = chunk & 3;
            int pd = ps ^ (row & 3);
            const __hip_bfloat16* ga = A + (size_t)(m0 + row) * LL + k0 + pd * 8;
            const __hip_bfloat16* gb = B + (size_t)(n0 + row) * LL + k0 + pd * 8;
            GLDS16(ga, (char*)As + (size_t)chunk * 16);
            GLDS16(gb, (char*)Bs + (size_t)chunk * 16);
        }
        __syncthreads();

        int lrow = lane & 15, part = lane >> 4;
        int sw = part ^ (lrow & 3);
        short8 afrag[4], bfrag[4];
#pragma unroll
        for (int i = 0; i < 4; ++i) {
            int slot = (wr * 64 + i * 16 + lrow) * 4 + sw;
            afrag[i] = *reinterpret_cast<const short8*>(As + (size_t)slot * 8);
        }
#pragma unroll
        for (int j = 0; j < 4; ++j) {
            int slot = (wc * 64 + j * 16 + lrow) * 4 + sw;
            bfrag[j] = *reinterpret_cast<const short8*>(Bs + (size_t)slot * 8);
        }
#pragma unroll
        for (int i = 0; i < 4; ++i)
#pragma unroll
            for (int j = 0; j < 4; ++j)
                acc[i][j] = __builtin_amdgcn_mfma_f32_16x16x32_bf16(afrag[i], bfrag[j], acc[i][j], 0, 0, 0);
        __syncthreads();
    }

    int col = lane & 15, rbase = (lane >> 4) * 4;
#pragma unroll
    for (int i = 0; i < 4; ++i)
#pragma unroll
        for (int j = 0; j < 4; ++j)
#pragma unroll
            for (int r = 0; r < 4; ++r) {
                int m = m0 + wr * 64 + i * 16 + rbase + r;
                int n = n0 + wc * 64 + j * 16 + col;
                C[(size_t)m * LL + n] = __float2bfloat16(acc[i][j][r]);
            }
}

// ---------------- correlation assembly (float4-vectorized + XCD-chunked swizzle) ----------------
// yi[p][q] = invn[p] * sum_{valid di,dj} D[p+48di+dj][q+48di+dj]
// T1: consecutive p share 6/9 stencil rows; chunked remap gives each XCD a contiguous
// 864-block (288-p) range -> D window ~3.5MB, L2-resident. Bijective: 6912 = 8*864.
__global__ __launch_bounds__(192) void k_corr_v4(const float* __restrict__ bufA, const float* __restrict__ invn,
                                                 float* __restrict__ bufB) {
    int sI = blockIdx.z;
    const float* D = bufA + sI * S_BUF;
    float* yi = bufB + sI * S_BUF;
    invn += (size_t)sI * LL;

    int f = blockIdx.y * 3 + blockIdx.x;         // x-fastest flatten = dispatch order
    int swz = (f & 7) * 864 + (f >> 3);          // 6912 = 8 * 864
    int p  = swz / 3;
    int qi = (swz % 3) * 192 + threadIdx.x;      // 0..575
    int q4 = qi * 4;
    int qh = q4 / GS, qw0 = q4 % GS;
    int ph = p / GS, pw = p % GS;

    float4 acc = {0.f, 0.f, 0.f, 0.f};
#pragma unroll
    for (int di = -1; di <= 1; ++di) {
        int rp = ph + di, tq = qh + di;
        if (rp < 0 || rp >= GS || tq < 0 || tq >= GS) continue;
        int r0 = rp * GS + pw;           // = p + 48*di
        int c0 = tq * GS + qw0;          // = q4 + 48*di (4-aligned)
        // dj = 0
        {
            float4 Cc = ld4(D + (size_t)r0 * LL + c0);
            acc.x += Cc.x; acc.y += Cc.y; acc.z += Cc.z; acc.w += Cc.w;
        }
        // dj = -1 (row r0-1, cols c0-1..c0+2); valid iff pw>0; elem0 masked iff qw0==0
        if (pw > 0) {
            const float* rowm = D + (size_t)(r0 - 1) * LL;
            float4 L  = ld4(rowm + (qw0 > 0 ? c0 - 4 : c0));
            float4 Cm = ld4(rowm + c0);
            acc.x += (qw0 > 0 ? L.w : 0.f);
            acc.y += Cm.x; acc.z += Cm.y; acc.w += Cm.z;
        }
        // dj = +1 (row r0+1, cols c0+1..c0+4); valid iff pw<47; elem3 masked iff qw0==44
        if (pw < GS - 1) {
            const float* rowp = D + (size_t)(r0 + 1) * LL;
            float4 Cp = ld4(rowp + c0);
            float4 R  = ld4(rowp + (qw0 < GS - 4 ? c0 + 4 : c0));
            acc.x += Cp.y; acc.y += Cp.z; acc.z += Cp.w;
            acc.w += (qw0 < GS - 4 ? R.x : 0.f);
        }
    }
    float inv = invn[p];
    float4 outv = {inv * acc.x, inv * acc.y, inv * acc.z, inv * acc.w};
    *reinterpret_cast<float4*>(yi + (size_t)p * LL + q4) = outv;
}

// ---------------- fuse1 (float4-vectorized + XCD-chunked swizzle): S1[a][b] = sum_d yi[a+d][b+d] ----------------
// T1: consecutive a share 2/3 rows; contiguous 288-a chunk per XCD -> ~2.7MB window.
__global__ __launch_bounds__(192) void k_fuse1_v4(const float* __restrict__ bufB, float* __restrict__ bufA) {
    int sI = blockIdx.z;
    const float* yi = bufB + sI * S_BUF;
    float* S1 = bufA + sI * S_BUF;

    int f = blockIdx.y * 3 + blockIdx.x;
    int swz = (f & 7) * 864 + (f >> 3);          // 6912 = 8 * 864
    int a  = swz / 3;
    int bi = (swz % 3) * 192 + threadIdx.x;
    int b4 = bi * 4;

    float4 acc = ld4(yi + (size_t)a * LL + b4);          // d = 0
    if (a > 0) {                                          // d = -1: cols b4-1..b4+2
        const float* rowm = yi + (size_t)(a - 1) * LL;
        float4 L  = ld4(rowm + (b4 > 0 ? b4 - 4 : b4));
        float4 Cm = ld4(rowm + b4);
        acc.x += (b4 > 0 ? L.w : 0.f);
        acc.y += Cm.x; acc.z += Cm.y; acc.w += Cm.z;
    }
    if (a < LL - 1) {                                     // d = +1: cols b4+1..b4+4
        const float* rowp = yi + (size_t)(a + 1) * LL;
        float4 Cp = ld4(rowp + b4);
        float4 R  = ld4(rowp + (b4 < LL - 4 ? b4 + 4 : b4));
        acc.x += Cp.y; acc.y += Cp.z; acc.z += Cp.w;
        acc.w += (b4 < LL - 4 ? R.x : 0.f);
    }
    *reinterpret_cast<float4*>(S1 + (size_t)a * LL + b4) = acc;
}

__device__ __forceinline__ int gmap(int x) { int hi = x / GS; int lo = x - hi * GS; return lo * GS + hi; }

// fuse2 + softmax partials, 4-wide, + XCD-chunked swizzle.
// gmap algebra: rows read are gmap(a0+e) ~= {p, p+-48} for p in the 32-chunk -> local;
// contiguous 9-chunk (288-p) range per XCD -> S1 window ~3.5MB, L2-resident.
// Bijective: 216 = 8*27.
__global__ __launch_bounds__(192) void k_fuse2_sm_v4(const float* __restrict__ bufA, const float* __restrict__ mmv,
                                                     float* __restrict__ bufB,
                                                     float* __restrict__ pmax, float* __restrict__ psum) {
    int sI = blockIdx.z;
    const float* S1 = bufA + sI * S_BUF;
    float* S2 = bufB + sI * S_BUF;
    mmv += (size_t)sI * LL; pmax += sI * S_PM; psum += sI * S_PM;

    int f = blockIdx.y * 3 + blockIdx.x;         // 0..215
    int swz = (f & 7) * 27 + (f >> 3);           // 216 = 8 * 27
    int yc = swz / 3;
    int qi = (swz % 3) * 192 + threadIdx.x;      // 0..575
    int q4 = qi * 4;
    int qh = q4 / GS, qw0 = q4 % GS;
    int p0 = yc * PCH2;
    float mxa[4], sma[4];
#pragma unroll
    for (int j = 0; j < 4; ++j) { mxa[j] = -1e30f; sma[j] = 0.f; }

    for (int i = 0; i < PCH2; ++i) {
        int p = p0 + i;
        int ph = p / GS, pw = p % GS;
        int a0 = pw * GS + ph;
        float sarr[4] = {0.f, 0.f, 0.f, 0.f};
#pragma unroll
        for (int e = -1; e <= 1; ++e) {
            int ae = a0 + e;
            if (ae < 0 || ae >= LL) continue;                 // uniform in block (p uniform)
            int Ar = gmap(ae);
            const float* Rw = S1 + (size_t)Ar * LL;
            int qe = qh + e;
            if (qe >= 0 && qe < GS) {                          // fast path: contiguous quad
                float4 v = ld4(Rw + q4 + 48 * e);
                sarr[0] += v.x; sarr[1] += v.y; sarr[2] += v.z; sarr[3] += v.w;
            } else {                                           // qh wrap: scalar gmap per element
#pragma unroll
                for (int j = 0; j < 4; ++j) {
                    int be = (qw0 + j) * GS + qh + e;
                    if (be >= 0 && be < LL) {
                        int bh = be / GS, bw = be % GS;
                        sarr[j] += Rw[bw * GS + bh];
                    }
                }
            }
        }
        float4 sv = {sarr[0], sarr[1], sarr[2], sarr[3]};
        *reinterpret_cast<float4*>(S2 + (size_t)p * LL + q4) = sv;
        float mv = mmv[p];
#pragma unroll
        for (int j = 0; j < 4; ++j) {
            float lg = (mv != 0.f) ? SCALE * sarr[j] : 0.f;
            float nm = fmaxf(mxa[j], lg);
            sma[j] = sma[j] * __expf(mxa[j] - nm) + __expf(lg - nm);
            mxa[j] = nm;
        }
    }
    float4 mo = {mxa[0], mxa[1], mxa[2], mxa[3]};
    float4 so = {sma[0], sma[1], sma[2], sma[3]};
    *reinterpret_cast<float4*>(pmax + (size_t)yc * LL + q4) = mo;
    *reinterpret_cast<float4*>(psum + (size_t)yc * LL + q4) = so;
}

// ---------------- sm3T + merged final softmax reduction ----------------
__global__ __launch_bounds__(256) void k_sm3T_full(const float* __restrict__ bufB, const float* __restrict__ mmv,
                                                   const float* __restrict__ pmax, const float* __restrict__ psum,
                                                   __hip_bfloat16* __restrict__ attnT) {
    __shared__ float tile[32][33];
    __shared__ float redM[8][32];
    __shared__ float redS[8][32];
    int sI = blockIdx.z;
    const float* S2 = bufB + sI * S_BUF;
    mmv += (size_t)sI * LL; pmax += sI * S_PM; psum += sI * S_PM; attnT += sI * S_AT;
    int t = threadIdx.x;
    int tx = t & 31, ty = t >> 5;        // ty doubles as reduction group
    int p0 = blockIdx.y * 32, q0 = blockIdx.x * 32;
    int q = q0 + tx;

    float mx = -1e30f;
    for (int ch = ty * 9; ch < ty * 9 + 9; ++ch)
        mx = fmaxf(mx, pmax[(size_t)ch * LL + q]);
    redM[ty][tx] = mx;
    __syncthreads();
    float mall = redM[0][tx];
#pragma unroll
    for (int g = 1; g < 8; ++g) mall = fmaxf(mall, redM[g][tx]);
    float sm = 0.f;
    for (int ch = ty * 9; ch < ty * 9 + 9; ++ch)
        sm += psum[(size_t)ch * LL + q] * __expf(pmax[(size_t)ch * LL + q] - mall);
    redS[ty][tx] = sm;
    __syncthreads();
    float dall = redS[0][tx];
#pragma unroll
    for (int g = 1; g < 8; ++g) dall += redS[g][tx];

    float mq = mall, dq = dall;
#pragma unroll
    for (int j = 0; j < 4; ++j) {
        int p = p0 + ty + 8 * j;
        float v = S2[(size_t)p * LL + q];
        float attn = (mmv[p] != 0.f) ? __expf(SCALE * v - mq) / dq : 0.f;
        tile[ty + 8 * j][tx] = attn;
    }
    __syncthreads();
#pragma unroll
    for (int j = 0; j < 4; ++j) {
        int qq = q0 + ty + 8 * j;
        attnT[(size_t)qq * LL + p0 + tx] = __float2bfloat16(tile[tx][ty + 8 * j]);
    }
}

// ---------------- output assembly (reads bf16 Zt [CKN][LL]) ----------------
__global__ __launch_bounds__(256) void k_out(const float* __restrict__ bufA, float* __restrict__ out) {
    int sI = blockIdx.z;
    const __hip_bfloat16* Z = (const __hip_bfloat16*)(bufA + sI * S_BUF);   // Zt [CKN][LL]
    out += sI * S_IN;
    int c  = blockIdx.y;
    int yx = blockIdx.x * 256 + threadIdx.x;     // gridDim.x = 36
    int y = yx / HW, x = yx % HW;
    int u = y >> 1, a = y & 1, v = x >> 1, w = x & 1;
    int qh1 = u + a - 1, qh2 = u + a, qw1 = v + w - 1, qw2 = v + w;
    int cb = c * 16;
    float s = 0.f;
    if (qh1 >= 0) {
        if (qw1 >= 0)  s += __bfloat162float(Z[(size_t)(cb + (3 - a) * 4 + (3 - w)) * LL + qh1 * GS + qw1]);
        if (qw2 < GS)  s += __bfloat162float(Z[(size_t)(cb + (3 - a) * 4 + (1 - w)) * LL + qh1 * GS + qw2]);
    }
    if (qh2 < GS) {
        if (qw1 >= 0)  s += __bfloat162float(Z[(size_t)(cb + (1 - a) * 4 + (3 - w)) * LL + qh2 * GS + qw1]);
        if (qw2 < GS)  s += __bfloat162float(Z[(size_t)(cb + (1 - a) * 4 + (1 - w)) * LL + qh2 * GS + qw2]);
    }
    out[(size_t)c * HW * HW + yx] = 0.25f * s;
}

// ---------------- launch (9 dispatches; no memset) ----------------

extern "C" void kernel_launch(void* const* d_in, const int* in_sizes, int n_in,
                              void* d_out, int out_size, void* d_ws, size_t ws_size,
                              hipStream_t stream) {
    const float* b_all = (const float*)d_in[0];
    const float* f_all = (const float*)d_in[1];
    const float* m_all = (const float*)d_in[2];
    float* out = (float*)d_out;
    float* ws  = (float*)d_ws;

    const size_t perF = 6 * (size_t)LL + 2 * S_PM + 2 * S_BUF + S_W2 / 2 + S_AT / 2;
    const size_t perB = perF * sizeof(float);
    int nb = (ws_size >= NS * perB) ? NS : ((ws_size >= 2 * perB) ? 2 : 1);

    size_t off = 0;
    float* ssq4 = ws + off; off += nb * 4 * (size_t)LL;
    float* invn = ws + off; off += nb * (size_t)LL;
    float* mmv  = ws + off; off += nb * (size_t)LL;
    float* pmax = ws + off; off += nb * S_PM;
    float* psum = ws + off; off += nb * S_PM;
    float* bufA = ws + off; off += nb * S_BUF;   // D -> S1 -> Zt(bf16)
    float* bufB = ws + off; off += nb * S_BUF;   // (splits) -> yi -> S2
    __hip_bfloat16* W2T   = (__hip_bfloat16*)(ws + off); off += nb * S_W2 / 2;
    __hip_bfloat16* attnT = (__hip_bfloat16*)(ws + off); off += nb * S_AT / 2;

    for (int s0 = 0; s0 < NS; s0 += nb) {
        const float* b  = b_all + s0 * S_IN;
        const float* f  = f_all + s0 * S_IN;
        const float* mk = m_all + s0 * S_MK;
        float* outp = out + s0 * S_IN;

        k_stage_split<<<dim3(72, 4, 2 * nb), 256, 0, stream>>>(b, f, ssq4, bufB);
        k_w2T_norm   <<<dim3(9, CKN, nb), 256, 0, stream>>>(b, mk, ssq4, invn, mmv, W2T);

        gemm1_mfma   <<<dim3(18, 18, nb), 256, 0, stream>>>(bufB, bufA);
        k_corr_v4    <<<dim3(3, LL, nb), 192, 0, stream>>>(bufA, invn, bufB);
        k_fuse1_v4   <<<dim3(3, LL, nb), 192, 0, stream>>>(bufB, bufA);
        k_fuse2_sm_v4<<<dim3(3, NCH2, nb), 192, 0, stream>>>(bufA, mmv, bufB, pmax, psum);

        k_sm3T_full  <<<dim3(72, 72, nb), 256, 0, stream>>>(bufB, mmv, pmax, psum, attnT);

        gemm2_mfma   <<<dim3(LL / 128, CKN / 128, nb), 256, 0, stream>>>(W2T, attnT, bufA);
        k_out        <<<dim3(36, CH, nb), 256, 0, stream>>>(bufA, outp);
    }
}

// Round 14
// 475.686 us; speedup vs baseline: 1.1503x; 1.0213x over previous
//
#include <hip/hip_runtime.h>
#include <hip/hip_bf16.h>
#include <math.h>

#define NS   4      // batch
#define CH   128    // channels
#define HW   96     // full-res H=W
#define GS   48     // half-res grid side
#define LL   2304   // GS*GS
#define CKN  2048   // CH*16 (4x4 taps)
#define SCALE 10.0f
#define EPSSUM 0.1152f  // 1152 * 1e-4
#define PCH2 32     // softmax p-chunk
#define NCH2 72     // 2304/32

// per-sample strides (elements)
#define S_IN  ((size_t)CH * HW * HW)   // b / f / out
#define S_MK  ((size_t)HW * HW)        // mask
#define S_PM  ((size_t)NCH2 * LL)      // pmax / psum
#define S_BUF ((size_t)LL * LL)        // bufA / bufB (fp32)
#define S_W2  ((size_t)CKN * LL)       // W2T (bf16 elems)
#define S_AT  ((size_t)LL * LL)        // attnT (bf16 elems)

typedef __attribute__((ext_vector_type(8))) short short8;
typedef __attribute__((ext_vector_type(4))) float float4v;

#define GLDS16(gptr, lptr) \
    __builtin_amdgcn_global_load_lds((const __attribute__((address_space(1))) void*)(gptr), \
        (__attribute__((address_space(3))) void*)(lptr), 16, 0, 0)

__device__ __forceinline__ float4 ld4(const float* p) { return *reinterpret_cast<const float4*>(p); }

// ---------------- fused staging: subsample + ssq partials + transposed hi/lo bf16 split ----------------
// (no swizzle: every source element read exactly once -> no inter-block reuse, T1 N/A)
__global__ __launch_bounds__(256) void k_stage_split(const float* __restrict__ b, const float* __restrict__ f,
                                                     float* __restrict__ ssq4, float* __restrict__ bufB) {
    __shared__ float tile[32][33];
    int z = blockIdx.z;
    int s = z >> 1, sel = z & 1;
    const float* X = (sel ? f : b) + s * S_IN;
    __hip_bfloat16* base = (__hip_bfloat16*)(bufB + s * S_BUF);
    __hip_bfloat16* hi = base + (size_t)sel * 2 * LL * CH;
    __hip_bfloat16* lo = hi + (size_t)LL * CH;
    int r0 = blockIdx.x * 32, c0 = blockIdx.y * 32;   // r0 over rs (LL), c0 over CH
    int tx = threadIdx.x & 31, ty = threadIdx.x >> 5;

#pragma unroll
    for (int j = 0; j < 4; ++j) {
        int c  = c0 + ty + 8 * j;
        int rs = r0 + tx;
        int r = rs / GS, ss_ = rs % GS;
        tile[ty + 8 * j][tx] = X[(size_t)c * HW * HW + (2 * r) * HW + 2 * ss_];
    }
    __syncthreads();

    if (sel == 0 && ty == 0) {
        float acc = 0.f;
        for (int cl = 0; cl < 32; ++cl) { float v = tile[cl][tx]; acc += v * v; }
        ssq4[(size_t)s * 4 * LL + (size_t)blockIdx.y * LL + r0 + tx] = acc;
    }

#pragma unroll
    for (int j = 0; j < 4; ++j) {
        int rl = ty + 8 * j, cl = tx;
        float v = tile[cl][rl];
        __hip_bfloat16 h = __float2bfloat16(v);
        float resid = v - __bfloat162float(h);
        hi[(size_t)(r0 + rl) * CH + c0 + cl] = h;
        lo[(size_t)(r0 + rl) * CH + c0 + cl] = __float2bfloat16(resid);
    }
}

// ---------------- W2T gather + (merged) norm/mask kernel ----------------
// T1 chunked swizzle: 16 ck's share one 36KB b c-plane; 18432 = 8*2304 -> each XCD
// owns 256 contiguous ck (16 c-planes). Norm part gates on swizzled ck == 0
// (exactly 9 blocks, px 0..8, unchanged semantics).
__global__ __launch_bounds__(256) void k_w2T_norm(const float* __restrict__ b, const float* __restrict__ mk,
                                                  const float* __restrict__ ssq4,
                                                  float* __restrict__ invn, float* __restrict__ mmv,
                                                  __hip_bfloat16* __restrict__ W2T) {
    int sI = blockIdx.z;
    int flat = blockIdx.y * 9 + blockIdx.x;          // 0..18431, dispatch order
    int swz  = (flat & 7) * 2304 + (flat >> 3);      // bijective: 18432 = 8 * 2304
    int ck = swz / 9;
    int px = swz % 9;
    {
        const float* bb = b + sI * S_IN;
        __hip_bfloat16* W = W2T + sI * S_W2;
        int p  = px * 256 + threadIdx.x;
        int c = ck >> 4, dy = (ck >> 2) & 3, dx = ck & 3;
        int ph = p / GS, pw = p % GS;
        int r = 2 * ph + dy - 1, s = 2 * pw + dx - 1;
        float v = 0.f;
        if (r >= 0 && r < HW && s >= 0 && s < HW) v = bb[c * HW * HW + r * HW + s];
        W[(size_t)ck * LL + p] = __float2bfloat16(v);
    }
    if (ck == 0) {
        const float* sq = ssq4 + (size_t)sI * 4 * LL;
        const float* m  = mk + sI * S_MK;
        float* iv = invn + (size_t)sI * LL;
        float* mv = mmv + (size_t)sI * LL;
        int p = px * 256 + threadIdx.x;
        int ph = p / GS, pw = p % GS;
        float acc = EPSSUM;
        float msum = 0.f;
        for (int di = -1; di <= 1; ++di)
            for (int dj = -1; dj <= 1; ++dj) {
                int r = ph + di, s = pw + dj;
                if (r >= 0 && r < GS && s >= 0 && s < GS) {
                    int idx = r * GS + s;
                    acc  += sq[idx] + sq[LL + idx] + sq[2 * LL + idx] + sq[3 * LL + idx];
                    msum += m[(2 * r) * HW + 2 * s];
                }
            }
        iv[p] = 1.0f / sqrtf(acc);
        mv[p] = (msum / 9.0f == 1.0f) ? 1.0f : 0.0f;
    }
}

// ---------------- GEMM1 (split-bf16 MFMA): D = bs fs^T over channels ----------------
// T1 general bijective swizzle (nwg = 324, 324 % 8 = 4 -> q=40, r=4 formula, m204):
// operand panels (2.4MB total) become per-XCD L2-resident instead of 8x-replicated.
__global__ __launch_bounds__(256) void gemm1_mfma(const float* __restrict__ bufB, float* __restrict__ bufA) {
    __shared__ __hip_bfloat16 sAh[128 * 32];
    __shared__ __hip_bfloat16 sAl[128 * 32];
    __shared__ __hip_bfloat16 sBh[128 * 32];
    __shared__ __hip_bfloat16 sBl[128 * 32];
    int sI = blockIdx.z;
    const __hip_bfloat16* base = (const __hip_bfloat16*)(bufB + sI * S_BUF);
    const __hip_bfloat16* Ahi = base;
    const __hip_bfloat16* Alo = Ahi + (size_t)LL * CH;
    const __hip_bfloat16* Bhi = Alo + (size_t)LL * CH;
    const __hip_bfloat16* Blo = Bhi + (size_t)LL * CH;
    float* C = bufA + sI * S_BUF;

    int t = threadIdx.x, lane = t & 63, w = t >> 6;
    int wr = w >> 1, wc = w & 1;

    int flat = blockIdx.y * 18 + blockIdx.x;         // 0..323
    int xcd = flat & 7, idx = flat >> 3;
    int swz = (xcd < 4 ? xcd * 41 : 164 + (xcd - 4) * 40) + idx;
    int by = swz / 18, bx = swz % 18;
    int m0 = by * 128, n0 = bx * 128;

    float4v acc[4][4];
#pragma unroll
    for (int i = 0; i < 4; ++i)
#pragma unroll
        for (int j = 0; j < 4; ++j) acc[i][j] = (float4v){0.f, 0.f, 0.f, 0.f};

    for (int k0 = 0; k0 < 128; k0 += 32) {
#pragma unroll
        for (int it = 0; it < 2; ++it) {
            int chunk = it * 256 + w * 64 + lane;
            int row = chunk >> 2, ps = chunk & 3;
            int pd = ps ^ (row & 3);
            size_t ga = (size_t)(m0 + row) * 128 + k0 + pd * 8;
            size_t gb = (size_t)(n0 + row) * 128 + k0 + pd * 8;
            GLDS16(Ahi + ga, (char*)sAh + (size_t)chunk * 16);
            GLDS16(Alo + ga, (char*)sAl + (size_t)chunk * 16);
            GLDS16(Bhi + gb, (char*)sBh + (size_t)chunk * 16);
            GLDS16(Blo + gb, (char*)sBl + (size_t)chunk * 16);
        }
        __syncthreads();

        int lrow = lane & 15, part = lane >> 4;
        int sw = part ^ (lrow & 3);
        short8 ah[4], al[4], bh[4], bl[4];
#pragma unroll
        for (int i = 0; i < 4; ++i) {
            int slot = (wr * 64 + i * 16 + lrow) * 4 + sw;
            ah[i] = *reinterpret_cast<const short8*>(sAh + (size_t)slot * 8);
            al[i] = *reinterpret_cast<const short8*>(sAl + (size_t)slot * 8);
        }
#pragma unroll
        for (int j = 0; j < 4; ++j) {
            int slot = (wc * 64 + j * 16 + lrow) * 4 + sw;
            bh[j] = *reinterpret_cast<const short8*>(sBh + (size_t)slot * 8);
            bl[j] = *reinterpret_cast<const short8*>(sBl + (size_t)slot * 8);
        }
#pragma unroll
        for (int i = 0; i < 4; ++i)
#pragma unroll
            for (int j = 0; j < 4; ++j) {
                acc[i][j] = __builtin_amdgcn_mfma_f32_16x16x32_bf16(ah[i], bh[j], acc[i][j], 0, 0, 0);
                acc[i][j] = __builtin_amdgcn_mfma_f32_16x16x32_bf16(ah[i], bl[j], acc[i][j], 0, 0, 0);
                acc[i][j] = __builtin_amdgcn_mfma_f32_16x16x32_bf16(al[i], bh[j], acc[i][j], 0, 0, 0);
            }
        __syncthreads();
    }

    int col = lane & 15, rbase = (lane >> 4) * 4;
#pragma unroll
    for (int i = 0; i < 4; ++i)
#pragma unroll
        for (int j = 0; j < 4; ++j)
#pragma unroll
            for (int r = 0; r < 4; ++r) {
                int m = m0 + wr * 64 + i * 16 + rbase + r;
                int n = n0 + wc * 64 + j * 16 + col;
                C[(size_t)m * LL + n] = acc[i][j][r];
            }
}

// ---------------- GEMM2 (bf16 MFMA, bf16 output, TRANSPOSED result) ----------------
// Proven R5 form + XCD swizzle. Structural per-K-step latency: closed for this session.
__global__ __launch_bounds__(256) void gemm2_mfma(const __hip_bfloat16* __restrict__ W2T_,
                                                  const __hip_bfloat16* __restrict__ attnT_,
                                                  float* __restrict__ bufA) {
    __shared__ __hip_bfloat16 As[128 * 32];
    __shared__ __hip_bfloat16 Bs[128 * 32];
    int sI = blockIdx.z;
    const __hip_bfloat16* A = W2T_ + sI * S_W2;        // [CKN][LL]
    const __hip_bfloat16* B = attnT_ + sI * S_AT;      // [LL][LL]
    __hip_bfloat16* C = (__hip_bfloat16*)(bufA + sI * S_BUF);   // Zt [CKN][LL]

    int t = threadIdx.x;
    int lane = t & 63, w = t >> 6;
    int wr = w >> 1, wc = w & 1;

    // bijective XCD swizzle (nwg = 288 = 8 * 36)
    int flat = blockIdx.y * 18 + blockIdx.x;
    int swz  = (flat & 7) * 36 + (flat >> 3);
    int by = swz / 18, bx = swz % 18;
    int m0 = by * 128, n0 = bx * 128;

    float4v acc[4][4];
#pragma unroll
    for (int i = 0; i < 4; ++i)
#pragma unroll
        for (int j = 0; j < 4; ++j) acc[i][j] = (float4v){0.f, 0.f, 0.f, 0.f};

    for (int k0 = 0; k0 < LL; k0 += 32) {
#pragma unroll
        for (int it = 0; it < 2; ++it) {
            int chunk = it * 256 + w * 64 + lane;
            int row = chunk >> 2, ps = chunk & 3;
            int pd = ps ^ (row & 3);
            const __hip_bfloat16* ga = A + (size_t)(m0 + row) * LL + k0 + pd * 8;
            const __hip_bfloat16* gb = B + (size_t)(n0 + row) * LL + k0 + pd * 8;
            GLDS16(ga, (char*)As + (size_t)chunk * 16);
            GLDS16(gb, (char*)Bs + (size_t)chunk * 16);
        }
        __syncthreads();

        int lrow = lane & 15, part = lane >> 4;
        int sw = part ^ (lrow & 3);
        short8 afrag[4], bfrag[4];
#pragma unroll
        for (int i = 0; i < 4; ++i) {
            int slot = (wr * 64 + i * 16 + lrow) * 4 + sw;
            afrag[i] = *reinterpret_cast<const short8*>(As + (size_t)slot * 8);
        }
#pragma unroll
        for (int j = 0; j < 4; ++j) {
            int slot = (wc * 64 + j * 16 + lrow) * 4 + sw;
            bfrag[j] = *reinterpret_cast<const short8*>(Bs + (size_t)slot * 8);
        }
#pragma unroll
        for (int i = 0; i < 4; ++i)
#pragma unroll
            for (int j = 0; j < 4; ++j)
                acc[i][j] = __builtin_amdgcn_mfma_f32_16x16x32_bf16(afrag[i], bfrag[j], acc[i][j], 0, 0, 0);
        __syncthreads();
    }

    int col = lane & 15, rbase = (lane >> 4) * 4;
#pragma unroll
    for (int i = 0; i < 4; ++i)
#pragma unroll
        for (int j = 0; j < 4; ++j)
#pragma unroll
            for (int r = 0; r < 4; ++r) {
                int m = m0 + wr * 64 + i * 16 + rbase + r;
                int n = n0 + wc * 64 + j * 16 + col;
                C[(size_t)m * LL + n] = __float2bfloat16(acc[i][j][r]);
            }
}

// ---------------- correlation assembly (float4-vectorized + XCD-chunked swizzle) ----------------
// T1 (validated R13, -34us with fuse1/fuse2): each XCD owns a contiguous 288-p range.
__global__ __launch_bounds__(192) void k_corr_v4(const float* __restrict__ bufA, const float* __restrict__ invn,
                                                 float* __restrict__ bufB) {
    int sI = blockIdx.z;
    const float* D = bufA + sI * S_BUF;
    float* yi = bufB + sI * S_BUF;
    invn += (size_t)sI * LL;

    int f = blockIdx.y * 3 + blockIdx.x;         // x-fastest flatten = dispatch order
    int swz = (f & 7) * 864 + (f >> 3);          // 6912 = 8 * 864
    int p  = swz / 3;
    int qi = (swz % 3) * 192 + threadIdx.x;      // 0..575
    int q4 = qi * 4;
    int qh = q4 / GS, qw0 = q4 % GS;
    int ph = p / GS, pw = p % GS;

    float4 acc = {0.f, 0.f, 0.f, 0.f};
#pragma unroll
    for (int di = -1; di <= 1; ++di) {
        int rp = ph + di, tq = qh + di;
        if (rp < 0 || rp >= GS || tq < 0 || tq >= GS) continue;
        int r0 = rp * GS + pw;           // = p + 48*di
        int c0 = tq * GS + qw0;          // = q4 + 48*di (4-aligned)
        // dj = 0
        {
            float4 Cc = ld4(D + (size_t)r0 * LL + c0);
            acc.x += Cc.x; acc.y += Cc.y; acc.z += Cc.z; acc.w += Cc.w;
        }
        // dj = -1 (row r0-1, cols c0-1..c0+2); valid iff pw>0; elem0 masked iff qw0==0
        if (pw > 0) {
            const float* rowm = D + (size_t)(r0 - 1) * LL;
            float4 L  = ld4(rowm + (qw0 > 0 ? c0 - 4 : c0));
            float4 Cm = ld4(rowm + c0);
            acc.x += (qw0 > 0 ? L.w : 0.f);
            acc.y += Cm.x; acc.z += Cm.y; acc.w += Cm.z;
        }
        // dj = +1 (row r0+1, cols c0+1..c0+4); valid iff pw<47; elem3 masked iff qw0==44
        if (pw < GS - 1) {
            const float* rowp = D + (size_t)(r0 + 1) * LL;
            float4 Cp = ld4(rowp + c0);
            float4 R  = ld4(rowp + (qw0 < GS - 4 ? c0 + 4 : c0));
            acc.x += Cp.y; acc.y += Cp.z; acc.z += Cp.w;
            acc.w += (qw0 < GS - 4 ? R.x : 0.f);
        }
    }
    float inv = invn[p];
    float4 outv = {inv * acc.x, inv * acc.y, inv * acc.z, inv * acc.w};
    *reinterpret_cast<float4*>(yi + (size_t)p * LL + q4) = outv;
}

// ---------------- fuse1 (float4-vectorized + XCD-chunked swizzle): S1[a][b] = sum_d yi[a+d][b+d] ----------------
__global__ __launch_bounds__(192) void k_fuse1_v4(const float* __restrict__ bufB, float* __restrict__ bufA) {
    int sI = blockIdx.z;
    const float* yi = bufB + sI * S_BUF;
    float* S1 = bufA + sI * S_BUF;

    int f = blockIdx.y * 3 + blockIdx.x;
    int swz = (f & 7) * 864 + (f >> 3);          // 6912 = 8 * 864
    int a  = swz / 3;
    int bi = (swz % 3) * 192 + threadIdx.x;
    int b4 = bi * 4;

    float4 acc = ld4(yi + (size_t)a * LL + b4);          // d = 0
    if (a > 0) {                                          // d = -1: cols b4-1..b4+2
        const float* rowm = yi + (size_t)(a - 1) * LL;
        float4 L  = ld4(rowm + (b4 > 0 ? b4 - 4 : b4));
        float4 Cm = ld4(rowm + b4);
        acc.x += (b4 > 0 ? L.w : 0.f);
        acc.y += Cm.x; acc.z += Cm.y; acc.w += Cm.z;
    }
    if (a < LL - 1) {                                     // d = +1: cols b4+1..b4+4
        const float* rowp = yi + (size_t)(a + 1) * LL;
        float4 Cp = ld4(rowp + b4);
        float4 R  = ld4(rowp + (b4 < LL - 4 ? b4 + 4 : b4));
        acc.x += Cp.y; acc.y += Cp.z; acc.z += Cp.w;
        acc.w += (b4 < LL - 4 ? R.x : 0.f);
    }
    *reinterpret_cast<float4*>(S1 + (size_t)a * LL + b4) = acc;
}

__device__ __forceinline__ int gmap(int x) { int hi = x / GS; int lo = x - hi * GS; return lo * GS + hi; }

// fuse2 + softmax partials, 4-wide, + XCD-chunked swizzle (validated R13).
__global__ __launch_bounds__(192) void k_fuse2_sm_v4(const float* __restrict__ bufA, const float* __restrict__ mmv,
                                                     float* __restrict__ bufB,
                                                     float* __restrict__ pmax, float* __restrict__ psum) {
    int sI = blockIdx.z;
    const float* S1 = bufA + sI * S_BUF;
    float* S2 = bufB + sI * S_BUF;
    mmv += (size_t)sI * LL; pmax += sI * S_PM; psum += sI * S_PM;

    int f = blockIdx.y * 3 + blockIdx.x;         // 0..215
    int swz = (f & 7) * 27 + (f >> 3);           // 216 = 8 * 27
    int yc = swz / 3;
    int qi = (swz % 3) * 192 + threadIdx.x;      // 0..575
    int q4 = qi * 4;
    int qh = q4 / GS, qw0 = q4 % GS;
    int p0 = yc * PCH2;
    float mxa[4], sma[4];
#pragma unroll
    for (int j = 0; j < 4; ++j) { mxa[j] = -1e30f; sma[j] = 0.f; }

    for (int i = 0; i < PCH2; ++i) {
        int p = p0 + i;
        int ph = p / GS, pw = p % GS;
        int a0 = pw * GS + ph;
        float sarr[4] = {0.f, 0.f, 0.f, 0.f};
#pragma unroll
        for (int e = -1; e <= 1; ++e) {
            int ae = a0 + e;
            if (ae < 0 || ae >= LL) continue;                 // uniform in block (p uniform)
            int Ar = gmap(ae);
            const float* Rw = S1 + (size_t)Ar * LL;
            int qe = qh + e;
            if (qe >= 0 && qe < GS) {                          // fast path: contiguous quad
                float4 v = ld4(Rw + q4 + 48 * e);
                sarr[0] += v.x; sarr[1] += v.y; sarr[2] += v.z; sarr[3] += v.w;
            } else {                                           // qh wrap: scalar gmap per element
#pragma unroll
                for (int j = 0; j < 4; ++j) {
                    int be = (qw0 + j) * GS + qh + e;
                    if (be >= 0 && be < LL) {
                        int bh = be / GS, bw = be % GS;
                        sarr[j] += Rw[bw * GS + bh];
                    }
                }
            }
        }
        float4 sv = {sarr[0], sarr[1], sarr[2], sarr[3]};
        *reinterpret_cast<float4*>(S2 + (size_t)p * LL + q4) = sv;
        float mv = mmv[p];
#pragma unroll
        for (int j = 0; j < 4; ++j) {
            float lg = (mv != 0.f) ? SCALE * sarr[j] : 0.f;
            float nm = fmaxf(mxa[j], lg);
            sma[j] = sma[j] * __expf(mxa[j] - nm) + __expf(lg - nm);
            mxa[j] = nm;
        }
    }
    float4 mo = {mxa[0], mxa[1], mxa[2], mxa[3]};
    float4 so = {sma[0], sma[1], sma[2], sma[3]};
    *reinterpret_cast<float4*>(pmax + (size_t)yc * LL + q4) = mo;
    *reinterpret_cast<float4*>(psum + (size_t)yc * LL + q4) = so;
}

// ---------------- sm3T + merged final softmax reduction ----------------
// T1 transposed-decode swizzle: the 72 blocks sharing q0 (same pmax/psum columns) are
// stride-72 in dispatch order; chunk over q-blocks (5184 = 8*648, 648 = 9 q-blocks x 72)
// so each XCD reads an 83KB pmax/psum slice instead of all 5.3MB.
__global__ __launch_bounds__(256) void k_sm3T_full(const float* __restrict__ bufB, const float* __restrict__ mmv,
                                                   const float* __restrict__ pmax, const float* __restrict__ psum,
                                                   __hip_bfloat16* __restrict__ attnT) {
    __shared__ float tile[32][33];
    __shared__ float redM[8][32];
    __shared__ float redS[8][32];
    int sI = blockIdx.z;
    const float* S2 = bufB + sI * S_BUF;
    mmv += (size_t)sI * LL; pmax += sI * S_PM; psum += sI * S_PM; attnT += sI * S_AT;
    int t = threadIdx.x;
    int tx = t & 31, ty = t >> 5;        // ty doubles as reduction group

    int flat = blockIdx.y * 72 + blockIdx.x;     // 0..5183, dispatch order
    int swz  = (flat & 7) * 648 + (flat >> 3);   // bijective: 5184 = 8 * 648
    int qb = swz / 72, pb = swz % 72;            // transposed decode: q-blocks contiguous per XCD
    int p0 = pb * 32, q0 = qb * 32;
    int q = q0 + tx;

    float mx = -1e30f;
    for (int ch = ty * 9; ch < ty * 9 + 9; ++ch)
        mx = fmaxf(mx, pmax[(size_t)ch * LL + q]);
    redM[ty][tx] = mx;
    __syncthreads();
    float mall = redM[0][tx];
#pragma unroll
    for (int g = 1; g < 8; ++g) mall = fmaxf(mall, redM[g][tx]);
    float sm = 0.f;
    for (int ch = ty * 9; ch < ty * 9 + 9; ++ch)
        sm += psum[(size_t)ch * LL + q] * __expf(pmax[(size_t)ch * LL + q] - mall);
    redS[ty][tx] = sm;
    __syncthreads();
    float dall = redS[0][tx];
#pragma unroll
    for (int g = 1; g < 8; ++g) dall += redS[g][tx];

    float mq = mall, dq = dall;
#pragma unroll
    for (int j = 0; j < 4; ++j) {
        int p = p0 + ty + 8 * j;
        float v = S2[(size_t)p * LL + q];
        float attn = (mmv[p] != 0.f) ? __expf(SCALE * v - mq) / dq : 0.f;
        tile[ty + 8 * j][tx] = attn;
    }
    __syncthreads();
#pragma unroll
    for (int j = 0; j < 4; ++j) {
        int qq = q0 + ty + 8 * j;
        attnT[(size_t)qq * LL + p0 + tx] = __float2bfloat16(tile[tx][ty + 8 * j]);
    }
}

// ---------------- output assembly (reads bf16 Zt [CKN][LL]) ----------------
// T1 chunked swizzle: 36 consecutive blocks share a 74KB Zt row-block (same c);
// 4608 = 8*576 -> each XCD owns 16 contiguous c's, row-blocks fetched once.
__global__ __launch_bounds__(256) void k_out(const float* __restrict__ bufA, float* __restrict__ out) {
    int sI = blockIdx.z;
    const __hip_bfloat16* Z = (const __hip_bfloat16*)(bufA + sI * S_BUF);   // Zt [CKN][LL]
    out += sI * S_IN;
    int flat = blockIdx.y * 36 + blockIdx.x;     // 0..4607, dispatch order
    int swz  = (flat & 7) * 576 + (flat >> 3);   // bijective: 4608 = 8 * 576
    int c  = swz / 36;
    int yx = (swz % 36) * 256 + threadIdx.x;
    int y = yx / HW, x = yx % HW;
    int u = y >> 1, a = y & 1, v = x >> 1, w = x & 1;
    int qh1 = u + a - 1, qh2 = u + a, qw1 = v + w - 1, qw2 = v + w;
    int cb = c * 16;
    float s = 0.f;
    if (qh1 >= 0) {
        if (qw1 >= 0)  s += __bfloat162float(Z[(size_t)(cb + (3 - a) * 4 + (3 - w)) * LL + qh1 * GS + qw1]);
        if (qw2 < GS)  s += __bfloat162float(Z[(size_t)(cb + (3 - a) * 4 + (1 - w)) * LL + qh1 * GS + qw2]);
    }
    if (qh2 < GS) {
        if (qw1 >= 0)  s += __bfloat162float(Z[(size_t)(cb + (1 - a) * 4 + (3 - w)) * LL + qh2 * GS + qw1]);
        if (qw2 < GS)  s += __bfloat162float(Z[(size_t)(cb + (1 - a) * 4 + (1 - w)) * LL + qh2 * GS + qw2]);
    }
    out[(size_t)c * HW * HW + yx] = 0.25f * s;
}

// ---------------- launch (9 dispatches; no memset) ----------------

extern "C" void kernel_launch(void* const* d_in, const int* in_sizes, int n_in,
                              void* d_out, int out_size, void* d_ws, size_t ws_size,
                              hipStream_t stream) {
    const float* b_all = (const float*)d_in[0];
    const float* f_all = (const float*)d_in[1];
    const float* m_all = (const float*)d_in[2];
    float* out = (float*)d_out;
    float* ws  = (float*)d_ws;

    const size_t perF = 6 * (size_t)LL + 2 * S_PM + 2 * S_BUF + S_W2 / 2 + S_AT / 2;
    const size_t perB = perF * sizeof(float);
    int nb = (ws_size >= NS * perB) ? NS : ((ws_size >= 2 * perB) ? 2 : 1);

    size_t off = 0;
    float* ssq4 = ws + off; off += nb * 4 * (size_t)LL;
    float* invn = ws + off; off += nb * (size_t)LL;
    float* mmv  = ws + off; off += nb * (size_t)LL;
    float* pmax = ws + off; off += nb * S_PM;
    float* psum = ws + off; off += nb * S_PM;
    float* bufA = ws + off; off += nb * S_BUF;   // D -> S1 -> Zt(bf16)
    float* bufB = ws + off; off += nb * S_BUF;   // (splits) -> yi -> S2
    __hip_bfloat16* W2T   = (__hip_bfloat16*)(ws + off); off += nb * S_W2 / 2;
    __hip_bfloat16* attnT = (__hip_bfloat16*)(ws + off); off += nb * S_AT / 2;

    for (int s0 = 0; s0 < NS; s0 += nb) {
        const float* b  = b_all + s0 * S_IN;
        const float* f  = f_all + s0 * S_IN;
        const float* mk = m_all + s0 * S_MK;
        float* outp = out + s0 * S_IN;

        k_stage_split<<<dim3(72, 4, 2 * nb), 256, 0, stream>>>(b, f, ssq4, bufB);
        k_w2T_norm   <<<dim3(9, CKN, nb), 256, 0, stream>>>(b, mk, ssq4, invn, mmv, W2T);

        gemm1_mfma   <<<dim3(18, 18, nb), 256, 0, stream>>>(bufB, bufA);
        k_corr_v4    <<<dim3(3, LL, nb), 192, 0, stream>>>(bufA, invn, bufB);
        k_fuse1_v4   <<<dim3(3, LL, nb), 192, 0, stream>>>(bufB, bufA);
        k_fuse2_sm_v4<<<dim3(3, NCH2, nb), 192, 0, stream>>>(bufA, mmv, bufB, pmax, psum);

        k_sm3T_full  <<<dim3(72, 72, nb), 256, 0, stream>>>(bufB, mmv, pmax, psum, attnT);

        gemm2_mfma   <<<dim3(LL / 128, CKN / 128, nb), 256, 0, stream>>>(W2T, attnT, bufA);
        k_out        <<<dim3(36, CH, nb), 256, 0, stream>>>(bufA, outp);
    }
}